// Round 7
// baseline (258.569 us; speedup 1.0000x reference)
//
#include <hip/hip_runtime.h>
#include <hip/hip_bf16.h>

#define B_ 8
#define K_ 8
#define H_ 256
#define W_ 256
#define HW (H_*W_)
#define NBLK 1024              // 128 blocks/batch, 2 rows/block, 2 px/thread
#define BPB  128

// ---------------------------------------------------------------------------
// helpers
// ---------------------------------------------------------------------------
__device__ __forceinline__ unsigned short f2bf(float f) {
    __hip_bfloat16 h = __float2bfloat16(f);  // RNE
    return *reinterpret_cast<unsigned short*>(&h);
}
// unpack 8 bf16 (elem 2k in low 16 bits, 2k+1 in high) to f32
__device__ __forceinline__ void ub8(uint4 u, float* o) {
    o[0] = __uint_as_float(u.x << 16); o[1] = __uint_as_float(u.x & 0xffff0000u);
    o[2] = __uint_as_float(u.y << 16); o[3] = __uint_as_float(u.y & 0xffff0000u);
    o[4] = __uint_as_float(u.z << 16); o[5] = __uint_as_float(u.z & 0xffff0000u);
    o[6] = __uint_as_float(u.w << 16); o[7] = __uint_as_float(u.w & 0xffff0000u);
}
// sum within each 32-lane half of a wave; result valid in lanes 0 and 32
__device__ __forceinline__ float half_reduce(float v) {
    v += __shfl_down(v, 16, 64);
    v += __shfl_down(v, 8, 64);
    v += __shfl_down(v, 4, 64);
    v += __shfl_down(v, 2, 64);
    v += __shfl_down(v, 1, 64);
    return v;
}
// fine-grained coherent (cache-bypassing) accesses — NO L2 fences anywhere
__device__ __forceinline__ void cstoref(float* p, float v) {
    __hip_atomic_store(p, v, __ATOMIC_RELAXED, __HIP_MEMORY_SCOPE_AGENT);
}
__device__ __forceinline__ float cloadf(const float* p) {
    return __hip_atomic_load((float*)p, __ATOMIC_RELAXED, __HIP_MEMORY_SCOPE_AGENT);
}
__device__ __forceinline__ void cstored(double* p, double v) {
    __hip_atomic_store(p, v, __ATOMIC_RELAXED, __HIP_MEMORY_SCOPE_AGENT);
}
__device__ __forceinline__ double cloadd(const double* p) {
    return __hip_atomic_load((double*)p, __ATOMIC_RELAXED, __HIP_MEMORY_SCOPE_AGENT);
}
__device__ __forceinline__ void cstoreu8(unsigned long long* p, unsigned long long v) {
    __hip_atomic_store(p, v, __ATOMIC_RELAXED, __HIP_MEMORY_SCOPE_AGENT);
}
__device__ __forceinline__ unsigned int cloadu(const unsigned int* p) {
    return __hip_atomic_load((unsigned int*)p, __ATOMIC_RELAXED, __HIP_MEMORY_SCOPE_AGENT);
}
// TIGHT-bounded spins (leader thread only): ~10 ms worst case per wait — a
// broken barrier becomes a fast wrong-answer-with-counters, never a hang.
__device__ __forceinline__ void wait_count(unsigned int* p, unsigned int target) {
    for (int i = 0; i < 20000; ++i) {
        if (cloadu(p) >= target) return;
        __builtin_amdgcn_s_sleep(1);
    }
}
// wait until the 4 split counters (stride 32 u32 = 128 B) sum to target
__device__ __forceinline__ void wait_sum4(unsigned int* base, unsigned int target) {
    for (int i = 0; i < 20000; ++i) {
        unsigned int s = cloadu(base) + cloadu(base + 32)
                       + cloadu(base + 64) + cloadu(base + 96);
        if (s >= target) return;
        __builtin_amdgcn_s_sleep(1);
    }
}

// per-pixel warp + bilinear + residual; TG fragment comes from registers
__device__ __forceinline__ void pixel_accum(
    const uint4* __restrict__ imgT,
    const uint4 t0, const uint4 g0, const uint4 g1,
    int b, int x, int y,
    float h00, float h01, float h02, float h10, float h11, float h12,
    float h20, float h21, float* aa) {
    const float X = (float)x - 127.5f, Y = (float)y - 127.5f;
    const float zw = h20 * X + h21 * Y + 1.f;
    const float Xw = (h00 * X + h01 * Y + h02) / zw + 127.5f;
    const float Yw = (h10 * X + h11 * Y + h12) / zw + 127.5f;
    const float NLO = -1.f + 2.f / 256.f, NHI = 1.f - 2.f / 256.f;
    const float xn = Xw / 127.5f - 1.f, yn = Yw / 127.5f - 1.f;
    const float m = (xn > NLO && xn < NHI && yn > NLO && yn < NHI) ? 1.f : 0.f;

    const float x0f = floorf(Xw), y0f = floorf(Yw);
    const float fx = Xw - x0f, fy = Yw - y0f;
    const float x1f = x0f + 1.f, y1f = y0f + 1.f;
    const bool vx0 = (x0f >= 0.f) && (x0f <= 255.f);
    const bool vx1 = (x1f >= 0.f) && (x1f <= 255.f);
    const bool vy0 = (y0f >= 0.f) && (y0f <= 255.f);
    const bool vy1 = (y1f >= 0.f) && (y1f <= 255.f);
    const int xi0 = (int)fminf(fmaxf(x0f, 0.f), 255.f);
    const int xi1 = (int)fminf(fmaxf(x1f, 0.f), 255.f);
    const int yi0 = (int)fminf(fmaxf(y0f, 0.f), 255.f);
    const int yi1 = (int)fminf(fmaxf(y1f, 0.f), 255.f);
    const int i00 = yi0 * W_ + xi0, i01 = yi0 * W_ + xi1;
    const int i10 = yi1 * W_ + xi0, i11 = yi1 * W_ + xi1;
    const float w00 = ((vx0 && vy0) ? 1.f : 0.f) * (1.f - fx) * (1.f - fy);
    const float w01 = ((vx1 && vy0) ? 1.f : 0.f) * fx * (1.f - fy);
    const float w10 = ((vx0 && vy1) ? 1.f : 0.f) * (1.f - fx) * fy;
    const float w11 = ((vx1 && vy1) ? 1.f : 0.f) * fx * fy;

    const int base = b * HW;
    const uint4 u00 = imgT[base + i00], u01 = imgT[base + i01];
    const uint4 u10 = imgT[base + i10], u11 = imgT[base + i11];

    float A00[8], A01[8], A10[8], A11[8], GXa[8], GYa[8], TV[8];
    ub8(u00, A00); ub8(u01, A01); ub8(u10, A10); ub8(u11, A11);
    ub8(t0, TV);   ub8(g0, GXa);  ub8(g1, GYa);

    float vx = 0.f, vy = 0.f;
    #pragma unroll
    for (int c = 0; c < 8; ++c) {
        const float Q = w00 * A00[c] + w01 * A01[c] + w10 * A10[c] + w11 * A11[c];
        const float r = Q - TV[c] * m;
        vx += GXa[c] * r;
        vy += GYa[c] * r;
    }
    const float t0a = X * vx, t4a = Y * vy;
    const float cc = t0a + t4a;
    aa[0] += t0a;      aa[1] += Y * vx;  aa[2] += vx;
    aa[3] += X * vy;   aa[4] += t4a;     aa[5] += vy;
    aa[6] -= X * cc;   aa[7] -= Y * cc;
}

// ---------------------------------------------------------------------------
// zero the 512 barrier counters (workspace is poisoned between runs).
// Normal stores; end-of-dispatch L2 writeback makes them visible to the
// fused kernel's uncached polls (empirically validated rounds 3-5).
// ---------------------------------------------------------------------------
__global__ void zero_bar_kernel(unsigned int* __restrict__ bar) {
    bar[threadIdx.x * 32] = 0u;   // 8 batches x 64 slots, one counter per 128B
}

// ---------------------------------------------------------------------------
// fully fused: prep + 10 iterations + inversion + output in ONE kernel.
// 1024 blocks x 256 thr, __launch_bounds__(256,2) — the only config proven
// spill-free (round 3: VGPR=100; both (..,4) variants clamped to 64 + spilled).
// Residency by capacity: LDS ~35 KB -> 4 blocks/CU; VGPR ~100 -> 5 blocks/CU;
// grid 1024 == 256 CU x 4. Block (b=blk&7, yb=blk>>3) owns rows 2yb..2yb+1.
//
// Prep: per row (2 sequential): stage 32 KB (8ch x {ym,y,yp,img}) -> grads ->
// TG packed DIRECTLY into iteration registers (never touches memory); imgT
// published with cache-bypassing stores; 15 row-moments -> 36 Gram entries
// (coherent f64). Per-batch prep barrier before iter 0's cross-row gathers.
//
// Barriers: 4-way SPLIT arrival counters per (batch, event): 128 arrivals
// become 4 parallel chains of 32 (waiter sums 4 counters). Slots per batch:
// it*4+part (0..39), prep 40..43, invH 44. No L2 fences anywhere.
// invH: computed once per batch (yb==0) during iter 0, published (slot 44).
// ---------------------------------------------------------------------------
__global__ __launch_bounds__(256, 2) void fused_kernel(
    const float* __restrict__ img, const float* __restrict__ temp,
    uint4* __restrict__ imgT, double* __restrict__ gramP,
    double* __restrict__ invHg, const float* __restrict__ init_param,
    float* __restrict__ sP0, float* __restrict__ sP1,
    unsigned int* __restrict__ bar,
    const int* __restrict__ max_itr, float* __restrict__ out) {
    __shared__ float smem[8192];      // 32 KB: prep staging/moments; iter red[]
    __shared__ float s15[15];
    __shared__ float s8[8];
    __shared__ double sh_invH[64];
    __shared__ double sh_pd[16];      // p (0..7), dp (8..15)
    __shared__ float sh_pf[8];
    __shared__ double gpart[144];
    __shared__ double shA[64], shB[64];

    const int tid = threadIdx.x;          // 0..255
    const int b   = blockIdx.x & 7;
    const int yb  = blockIdx.x >> 3;      // 0..127
    unsigned int* bbar = bar + (size_t)b * 64 * 32;
    const int part = yb & 3;
    const int mi_raw = *max_itr;
    const int mi = (mi_raw > 10) ? 10 : mi_raw;

    // ================= PREP phase (TG straight into registers) =============
    uint4 rT[2], rGX[2], rGY[2];
    #pragma unroll 1
    for (int rl = 0; rl < 2; ++rl) {
        const int y  = yb * 2 + rl;
        const int ym = (y > 0) ? y - 1 : 0;
        const int yp = (y < 255) ? y + 1 : 255;
        __syncthreads();                  // smem free (prev row consumed)
        #pragma unroll
        for (int j = 0; j < 8; ++j) {
            const int slot = tid + 256 * j;
            const int rowid = slot >> 6, col4 = slot & 63;
            const int c = rowid >> 2, sel = rowid & 3;
            const int sy = (sel == 0) ? ym : ((sel == 2) ? yp : y);
            const float* src = ((sel == 3) ? img : temp)
                             + ((size_t)(b * K_ + c) * HW + sy * W_ + col4 * 4);
            const float4 v = *(const float4*)src;
            *(float4*)&smem[(c * 4 + sel) * 256 + col4 * 4] = v;
        }
        __syncthreads();

        const int x = tid;
        const int xm = (x > 0) ? x - 1 : 0;
        const int xp = (x < 255) ? x + 1 : 255;
        float Sxx = 0.f, Sxy = 0.f, Syy = 0.f;
        unsigned int imgp[4] = {0, 0, 0, 0};
        unsigned int tgp[12];
        #pragma unroll
        for (int i = 0; i < 12; ++i) tgp[i] = 0u;
        #pragma unroll
        for (int c = 0; c < 8; ++c) {
            const float* R = &smem[c * 1024];
            const float gx = 0.5f * (R[256 + xp] - R[256 + xm]);
            const float gy = 0.5f * (R[512 + x] - R[x]);
            const float tc = R[256 + x];
            const float iv = R[768 + x];
            Sxx += gx * gx; Sxy += gx * gy; Syy += gy * gy;
            const int sh = (c & 1) * 16;
            imgp[c >> 1]     |= ((unsigned int)f2bf(iv)) << sh;
            tgp[c >> 1]      |= ((unsigned int)f2bf(tc)) << sh;
            tgp[4 + (c >> 1)]|= ((unsigned int)f2bf(gx)) << sh;
            tgp[8 + (c >> 1)]|= ((unsigned int)f2bf(gy)) << sh;
        }
        // publish imgT (write-through 8B stores; poison lines were flushed at
        // the fill dispatch's end, so cached re-reads post-barrier are safe)
        {
            const size_t gpx = (size_t)b * HW + (size_t)y * W_ + x;
            unsigned long long* ip = (unsigned long long*)(imgT + gpx);
            cstoreu8(ip,     ((unsigned long long)imgp[1] << 32) | imgp[0]);
            cstoreu8(ip + 1, ((unsigned long long)imgp[3] << 32) | imgp[2]);
        }
        rT[rl]  = make_uint4(tgp[0], tgp[1], tgp[2],  tgp[3]);
        rGX[rl] = make_uint4(tgp[4], tgp[5], tgp[6],  tgp[7]);
        rGY[rl] = make_uint4(tgp[8], tgp[9], tgp[10], tgp[11]);
        __syncthreads();                  // rows consumed; reuse smem

        // ---- 15 row-moments ----
        {
            const float X = (float)x - 127.5f;
            const float X2 = X * X;
            const float Xp[5] = {1.f, X, X2, X2 * X, X2 * X2};
            #pragma unroll
            for (int n = 0; n < 5; ++n) {
                smem[n * 256 + tid]        = Sxx * Xp[n];
                smem[(5 + n) * 256 + tid]  = Sxy * Xp[n];
                smem[(10 + n) * 256 + tid] = Syy * Xp[n];
            }
        }
        __syncthreads();
        {
            const int e = tid >> 5, l = tid & 31;
            float v = 0.f;
            #pragma unroll
            for (int j = 0; j < 8; ++j) v += smem[e * 256 + l + 32 * j];
            v = half_reduce(v);
            if (l == 0) s15[e] = v;
        }
        if (tid < 224) {
            const int e = 8 + (tid >> 5), l = tid & 31;
            float v = 0.f;
            #pragma unroll
            for (int j = 0; j < 8; ++j) v += smem[e * 256 + l + 32 * j];
            v = half_reduce(v);
            if (l == 0) s15[e] = v;
        }
        __syncthreads();

        // ---- 36 upper-tri Gram entries for this row (coherent f64) ----
        if (tid < 36) {
            const int aC[8]  = {1, 1, 1, 0, 0, 0, -1, -1};
            const int aNX[8] = {1, 0, 0, 0, 0, 0,  2,  1};
            const int aNY[8] = {0, 1, 0, 0, 0, 0,  0,  1};
            const int bC[8]  = {0, 0, 0, 1, 1, 1, -1, -1};
            const int bNX[8] = {0, 0, 0, 1, 0, 0,  1,  0};
            const int bNY[8] = {0, 0, 0, 0, 1, 0,  1,  2};
            const double Yd = (double)((float)y - 127.5f);
            const double Yp2 = Yd * Yd;
            const double Ypw[5] = {1.0, Yd, Yp2, Yp2 * Yd, Yp2 * Yp2};
            int p = 0, rem = tid;
            while (rem >= 8 - p) { rem -= 8 - p; ++p; }
            const int q = p + rem;
            double g = 0.0;
            const int ac = aC[p] * aC[q];
            if (ac) g += ac * Ypw[aNY[p] + aNY[q]] * (double)s15[aNX[p] + aNX[q]];
            const int ab1 = aC[p] * bC[q];
            if (ab1) g += ab1 * Ypw[aNY[p] + bNY[q]] * (double)s15[5 + aNX[p] + bNX[q]];
            const int ab2 = bC[p] * aC[q];
            if (ab2) g += ab2 * Ypw[bNY[p] + aNY[q]] * (double)s15[5 + bNX[p] + aNX[q]];
            const int bc = bC[p] * bC[q];
            if (bc) g += bc * Ypw[bNY[p] + bNY[q]] * (double)s15[10 + bNX[p] + bNX[q]];
            cstored(&gramP[((size_t)b * 36 + tid) * 256 + y], g);
        }
    }

    // ---- prep barrier: all 128 blocks of batch published imgT + gramP ----
    asm volatile("s_waitcnt vmcnt(0)" ::: "memory");
    __syncthreads();
    if (tid == 0) {
        __hip_atomic_fetch_add(&bbar[(40 + part) * 32], 1u,
                               __ATOMIC_RELAXED, __HIP_MEMORY_SCOPE_AGENT);
        wait_sum4(&bbar[40 * 32], 128u);
    }
    __syncthreads();

    // ========================= ITERATION phase =============================
    for (int it = 0; it < mi; ++it) {
        if (it > 0) {
            if (tid == 0) {
                wait_sum4(&bbar[(it - 1) * 4 * 32], 128u);
                if (it == 1) wait_count(&bbar[44 * 32], 1u);
            }
            __syncthreads();
            if (it == 1 && tid < 64) sh_invH[tid] = cloadd(&invHg[b * 64 + tid]);
            {
                const float* sR = ((it & 1) ? sP0 : sP1) + b * 1024;
                const int e = tid >> 5, l = tid & 31;
                float v = cloadf(&sR[e * 128 + l])      + cloadf(&sR[e * 128 + 32 + l])
                        + cloadf(&sR[e * 128 + 64 + l]) + cloadf(&sR[e * 128 + 96 + l]);
                v = half_reduce(v);
                if (l == 0) s8[e] = v;
            }
            __syncthreads();
            if (tid < 8) {
                double nrm2 = 0.0;
                #pragma unroll
                for (int k2 = 0; k2 < 8; ++k2) {
                    const double d = sh_pd[8 + k2];
                    nrm2 += d * d;
                }
                double dpn = 0.0;
                if (tid < 6) {
                    #pragma unroll
                    for (int k2 = 0; k2 < 8; ++k2)
                        dpn += sh_invH[tid * 8 + k2] * (double)s8[k2];
                }
                const double dp2 = (sqrt(nrm2) > 1e-3) ? dpn : 0.0;
                const double pnew = sh_pd[tid] - dp2;
                sh_pd[tid]     = pnew;
                sh_pd[8 + tid] = dp2;
            }
            __syncthreads();
        } else {
            if (tid < 8) {
                sh_pd[tid]     = (double)init_param[b * 8 + tid];
                sh_pd[8 + tid] = 1.0;
            }
            __syncthreads();
        }

        const float h00 = 1.f + (float)sh_pd[0], h01 = (float)sh_pd[1], h02 = (float)sh_pd[2];
        const float h10 = (float)sh_pd[3], h11 = 1.f + (float)sh_pd[4], h12 = (float)sh_pd[5];
        const float h20 = (float)sh_pd[6], h21 = (float)sh_pd[7];

        // ---- pixel phase: 2 px/thread (same rows the thread prepped) ----
        float aa[8];
        #pragma unroll
        for (int e = 0; e < 8; ++e) aa[e] = 0.f;
        #pragma unroll
        for (int sub = 0; sub < 2; ++sub) {
            pixel_accum(imgT, rT[sub], rGX[sub], rGY[sub], b,
                        tid, yb * 2 + sub,
                        h00, h01, h02, h10, h11, h12, h20, h21, aa);
        }

        // ---- block reduce (red overlays smem) -> 8 coherent partials ----
        float* red = smem;
        #pragma unroll
        for (int e = 0; e < 8; ++e) red[e * 256 + tid] = aa[e];
        __syncthreads();
        {
            const int e = tid >> 5, l = tid & 31;
            float v = 0.f;
            #pragma unroll
            for (int j = 0; j < 8; ++j) v += red[e * 256 + l + 32 * j];
            v = half_reduce(v);
            if (l == 0) {
                float* sW = (it & 1) ? sP1 : sP0;
                cstoref(&sW[b * 1024 + e * 128 + yb], v);
            }
        }

        // ---- arrive (split counter) ----
        asm volatile("s_waitcnt vmcnt(0)" ::: "memory");
        __syncthreads();
        if (tid == 0)
            __hip_atomic_fetch_add(&bbar[(it * 4 + part) * 32], 1u,
                                   __ATOMIC_RELAXED, __HIP_MEMORY_SCOPE_AGENT);

        // ---- iter 0, yb==0: Gram reduce + f64 Gauss-Jordan, publish invH ----
        if (it == 0 && yb == 0) {
            if (tid < 144) {
                const int e = tid >> 2, q = tid & 3;
                const double* gp = gramP + ((size_t)b * 36 + e) * 256 + q * 64;
                double acc = 0.0;
                #pragma unroll 8
                for (int i = 0; i < 64; ++i) acc += cloadd(&gp[i]);
                gpart[tid] = acc;
            }
            __syncthreads();
            const int i = tid >> 3, j = tid & 7;
            if (tid < 64) {
                const int pp = min(i, j), qq = max(i, j);
                const int tri = 8 * pp - (pp * (pp - 1)) / 2 + (qq - pp);
                shA[tid] = gpart[tri * 4] + gpart[tri * 4 + 1]
                         + gpart[tri * 4 + 2] + gpart[tri * 4 + 3];
                shB[tid] = (i == j) ? 1.0 : 0.0;
            }
            __syncthreads();
            for (int k = 0; k < 8; ++k) {
                const double piv = shA[k * 8 + k];
                __syncthreads();
                if (tid < 64 && i == k) { shA[tid] /= piv; shB[tid] /= piv; }
                __syncthreads();
                double f = 0, ak = 0, bk = 0;
                if (tid < 64) { f = shA[i * 8 + k]; ak = shA[k * 8 + j]; bk = shB[k * 8 + j]; }
                __syncthreads();
                if (tid < 64 && i != k) { shA[tid] -= f * ak; shB[tid] -= f * bk; }
                __syncthreads();
            }
            if (tid < 64) cstored(&invHg[b * 64 + tid], shB[tid]);
            asm volatile("s_waitcnt vmcnt(0)" ::: "memory");
            __syncthreads();
            if (tid == 0)
                __hip_atomic_fetch_add(&bbar[44 * 32], 1u,
                                       __ATOMIC_RELAXED, __HIP_MEMORY_SCOPE_AGENT);
        }
    }

    // ========================= OUTPUT phase ================================
    if (yb != 0) return;                  // 8 blocks, one per batch
    if (mi <= 0) {
        if (tid < 8) out[b * 8 + tid] = init_param[b * 8 + tid];
        if (tid < 9) {
            float v = (tid < 8) ? init_param[b * 8 + tid] : 0.f;
            if (tid == 0 || tid == 4 || tid == 8) v += 1.f;
            out[64 + b * 9 + tid] = v;
        }
        return;
    }
    if (tid == 0) wait_sum4(&bbar[(mi - 1) * 4 * 32], 128u);
    __syncthreads();
    // mi==1: iter-1 recon never ran, but this block computed invHg itself
    if (mi == 1 && tid < 64) sh_invH[tid] = cloadd(&invHg[b * 64 + tid]);
    {
        const float* sb = (((mi - 1) & 1) ? sP1 : sP0) + b * 1024;
        const int e = tid >> 5, l = tid & 31;
        float v = cloadf(&sb[e * 128 + l])      + cloadf(&sb[e * 128 + 32 + l])
                + cloadf(&sb[e * 128 + 64 + l]) + cloadf(&sb[e * 128 + 96 + l]);
        v = half_reduce(v);
        if (l == 0) s8[e] = v;
    }
    __syncthreads();
    if (tid < 8) {
        double nrm2 = 0.0;
        #pragma unroll
        for (int k2 = 0; k2 < 8; ++k2) {
            const double d = sh_pd[8 + k2];     // dp of last iteration
            nrm2 += d * d;
        }
        double dpn = 0.0;
        if (tid < 6) {
            #pragma unroll
            for (int k2 = 0; k2 < 8; ++k2)
                dpn += sh_invH[tid * 8 + k2] * (double)s8[k2];
        }
        const double dp2 = (sqrt(nrm2) > 1e-3) ? dpn : 0.0;
        const float pf = (float)(sh_pd[tid] - dp2);
        sh_pf[tid] = pf;
        out[b * 8 + tid] = pf;
    }
    __syncthreads();
    if (tid < 9) {
        float v2 = (tid < 8) ? sh_pf[tid] : 0.f;
        if (tid == 0 || tid == 4 || tid == 8) v2 += 1.f;
        out[64 + b * 9 + tid] = v2;
    }
}

extern "C" void kernel_launch(void* const* d_in, const int* in_sizes, int n_in,
                              void* d_out, int out_size, void* d_ws, size_t ws_size,
                              hipStream_t stream) {
    const float* img        = (const float*)d_in[0];
    const float* temp       = (const float*)d_in[1];
    const float* init_param = (const float*)d_in[2];
    const int*   max_itr    = (const int*)d_in[3];
    float* out = (float*)d_out;

    char* w = (char*)d_ws;
    double* gramP = (double*)w;                        // 8*36*256 d = 576 KB
    double* invHg = gramP + 73728;                     // 512 d = 4 KB
    float*  sP0   = (float*)(invHg + 512);             // 8192 f = 32 KB
    float*  sP1   = sP0 + 8192;                        // 32 KB
    unsigned int* bar = (unsigned int*)(sP1 + 8192);   // 512 x 128 B = 64 KB
    uint4* imgT   = (uint4*)(w + 1048576);             // 8.39 MB (bf16 x8 / px)

    zero_bar_kernel<<<1, 512, 0, stream>>>(bar);
    // residency by capacity: grid 1024 == 256 CU x 4; LDS ~35 KB -> 4/CU,
    // VGPR ~100 (launch_bounds(256,2), proven in round 3) -> 5/CU.
    fused_kernel<<<NBLK, 256, 0, stream>>>(img, temp, imgT, gramP, invHg,
                                           init_param, sP0, sP1, bar,
                                           max_itr, out);
}

// Round 8
// 254.104 us; speedup vs baseline: 1.0176x; 1.0176x over previous
//
#include <hip/hip_runtime.h>
#include <hip/hip_bf16.h>

#define B_ 8
#define K_ 8
#define H_ 256
#define W_ 256
#define HW (H_*W_)
#define NBLK 1024              // 128 blocks/batch, 2 rows/block, 2 px/thread
#define BPB  128

// ---------------------------------------------------------------------------
// helpers
// ---------------------------------------------------------------------------
__device__ __forceinline__ unsigned short f2bf(float f) {
    __hip_bfloat16 h = __float2bfloat16(f);  // RNE
    return *reinterpret_cast<unsigned short*>(&h);
}
// extract bf16 channel c (elem 2k in low 16 bits, 2k+1 in high) as f32.
// c is compile-time under #pragma unroll -> pure shift/mask, no arrays.
__device__ __forceinline__ float bfex(uint4 u, int c) {
    const unsigned int w = (&u.x)[c >> 1];
    return __uint_as_float((c & 1) ? (w & 0xffff0000u) : (w << 16));
}
// sum within each 32-lane half of a wave; result valid in lanes 0 and 32
__device__ __forceinline__ float half_reduce(float v) {
    v += __shfl_down(v, 16, 64);
    v += __shfl_down(v, 8, 64);
    v += __shfl_down(v, 4, 64);
    v += __shfl_down(v, 2, 64);
    v += __shfl_down(v, 1, 64);
    return v;
}
// fine-grained coherent (cache-bypassing) accesses — NO L2 fences anywhere
__device__ __forceinline__ void cstoref(float* p, float v) {
    __hip_atomic_store(p, v, __ATOMIC_RELAXED, __HIP_MEMORY_SCOPE_AGENT);
}
__device__ __forceinline__ float cloadf(const float* p) {
    return __hip_atomic_load((float*)p, __ATOMIC_RELAXED, __HIP_MEMORY_SCOPE_AGENT);
}
__device__ __forceinline__ void cstored(double* p, double v) {
    __hip_atomic_store(p, v, __ATOMIC_RELAXED, __HIP_MEMORY_SCOPE_AGENT);
}
__device__ __forceinline__ double cloadd(const double* p) {
    return __hip_atomic_load((double*)p, __ATOMIC_RELAXED, __HIP_MEMORY_SCOPE_AGENT);
}
__device__ __forceinline__ void cstoreu8(unsigned long long* p, unsigned long long v) {
    __hip_atomic_store(p, v, __ATOMIC_RELAXED, __HIP_MEMORY_SCOPE_AGENT);
}
__device__ __forceinline__ unsigned int cloadu(const unsigned int* p) {
    return __hip_atomic_load((unsigned int*)p, __ATOMIC_RELAXED, __HIP_MEMORY_SCOPE_AGENT);
}
// TIGHT-bounded spins (leader thread only): ~10 ms worst case per wait — a
// broken barrier becomes a fast wrong-answer-with-counters, never a hang.
__device__ __forceinline__ void wait_count(unsigned int* p, unsigned int target) {
    for (int i = 0; i < 20000; ++i) {
        if (cloadu(p) >= target) return;
        __builtin_amdgcn_s_sleep(1);
    }
}
// wait until the 4 split counters (stride 32 u32 = 128 B) sum to target
__device__ __forceinline__ void wait_sum4(unsigned int* base, unsigned int target) {
    for (int i = 0; i < 20000; ++i) {
        unsigned int s = cloadu(base) + cloadu(base + 32)
                       + cloadu(base + 64) + cloadu(base + 96);
        if (s >= target) return;
        __builtin_amdgcn_s_sleep(1);
    }
}

// per-pixel warp + bilinear + residual; TG fragment comes from registers.
// REGISTER-SLIM: channels extracted at use time (bfex) — no unpack arrays.
// Arithmetic is bit-identical to the array form (same values, same order);
// live set ~55 VGPR so the compiler's 64-VGPR allocation doesn't spill
// (round 5/7: 7x8 unpack arrays at VGPR=64 -> ~70 MB scratch traffic).
__device__ __forceinline__ void pixel_accum(
    const uint4* __restrict__ imgT,
    const uint4 t0, const uint4 g0, const uint4 g1,
    int b, int x, int y,
    float h00, float h01, float h02, float h10, float h11, float h12,
    float h20, float h21, float* aa) {
    const float X = (float)x - 127.5f, Y = (float)y - 127.5f;
    const float zw = h20 * X + h21 * Y + 1.f;
    const float Xw = (h00 * X + h01 * Y + h02) / zw + 127.5f;
    const float Yw = (h10 * X + h11 * Y + h12) / zw + 127.5f;
    const float NLO = -1.f + 2.f / 256.f, NHI = 1.f - 2.f / 256.f;
    const float xn = Xw / 127.5f - 1.f, yn = Yw / 127.5f - 1.f;
    const float m = (xn > NLO && xn < NHI && yn > NLO && yn < NHI) ? 1.f : 0.f;

    const float x0f = floorf(Xw), y0f = floorf(Yw);
    const float fx = Xw - x0f, fy = Yw - y0f;
    const float x1f = x0f + 1.f, y1f = y0f + 1.f;
    const bool vx0 = (x0f >= 0.f) && (x0f <= 255.f);
    const bool vx1 = (x1f >= 0.f) && (x1f <= 255.f);
    const bool vy0 = (y0f >= 0.f) && (y0f <= 255.f);
    const bool vy1 = (y1f >= 0.f) && (y1f <= 255.f);
    const int xi0 = (int)fminf(fmaxf(x0f, 0.f), 255.f);
    const int xi1 = (int)fminf(fmaxf(x1f, 0.f), 255.f);
    const int yi0 = (int)fminf(fmaxf(y0f, 0.f), 255.f);
    const int yi1 = (int)fminf(fmaxf(y1f, 0.f), 255.f);
    const int i00 = yi0 * W_ + xi0, i01 = yi0 * W_ + xi1;
    const int i10 = yi1 * W_ + xi0, i11 = yi1 * W_ + xi1;
    const float w00 = ((vx0 && vy0) ? 1.f : 0.f) * (1.f - fx) * (1.f - fy);
    const float w01 = ((vx1 && vy0) ? 1.f : 0.f) * fx * (1.f - fy);
    const float w10 = ((vx0 && vy1) ? 1.f : 0.f) * (1.f - fx) * fy;
    const float w11 = ((vx1 && vy1) ? 1.f : 0.f) * fx * fy;

    const int base = b * HW;
    const uint4 u00 = imgT[base + i00], u01 = imgT[base + i01];
    const uint4 u10 = imgT[base + i10], u11 = imgT[base + i11];

    float vx = 0.f, vy = 0.f;
    #pragma unroll
    for (int c = 0; c < 8; ++c) {
        const float Q = w00 * bfex(u00, c) + w01 * bfex(u01, c)
                      + w10 * bfex(u10, c) + w11 * bfex(u11, c);
        const float r = Q - bfex(t0, c) * m;
        vx += bfex(g0, c) * r;
        vy += bfex(g1, c) * r;
    }
    const float t0a = X * vx, t4a = Y * vy;
    const float cc = t0a + t4a;
    aa[0] += t0a;      aa[1] += Y * vx;  aa[2] += vx;
    aa[3] += X * vy;   aa[4] += t4a;     aa[5] += vy;
    aa[6] -= X * cc;   aa[7] -= Y * cc;
}

// ---------------------------------------------------------------------------
// zero the 512 barrier counters (workspace is poisoned between runs).
// ---------------------------------------------------------------------------
__global__ void zero_bar_kernel(unsigned int* __restrict__ bar) {
    bar[threadIdx.x * 32] = 0u;   // 8 batches x 64 slots, one counter per 128B
}

// ---------------------------------------------------------------------------
// fully fused: prep + 10 iterations + inversion + output in ONE kernel.
// 1024 blocks x 256 thr, __launch_bounds__(256,2). Block (b=blk&7, yb=blk>>3)
// owns rows 2yb..2yb+1. Identical to round 7 (passed, sync proven) except the
// register-slim pixel_accum. Barriers: 4-way split arrival counters per
// (batch,event); slots it*4+part (0..39), prep 40..43, invH 44. No L2 fences.
// ---------------------------------------------------------------------------
__global__ __launch_bounds__(256, 2) void fused_kernel(
    const float* __restrict__ img, const float* __restrict__ temp,
    uint4* __restrict__ imgT, double* __restrict__ gramP,
    double* __restrict__ invHg, const float* __restrict__ init_param,
    float* __restrict__ sP0, float* __restrict__ sP1,
    unsigned int* __restrict__ bar,
    const int* __restrict__ max_itr, float* __restrict__ out) {
    __shared__ float smem[8192];      // 32 KB: prep staging/moments; iter red[]
    __shared__ float s15[15];
    __shared__ float s8[8];
    __shared__ double sh_invH[64];
    __shared__ double sh_pd[16];      // p (0..7), dp (8..15)
    __shared__ float sh_pf[8];
    __shared__ double gpart[144];
    __shared__ double shA[64], shB[64];

    const int tid = threadIdx.x;          // 0..255
    const int b   = blockIdx.x & 7;
    const int yb  = blockIdx.x >> 3;      // 0..127
    unsigned int* bbar = bar + (size_t)b * 64 * 32;
    const int part = yb & 3;
    const int mi_raw = *max_itr;
    const int mi = (mi_raw > 10) ? 10 : mi_raw;

    // ================= PREP phase (TG straight into registers) =============
    uint4 rT[2], rGX[2], rGY[2];
    #pragma unroll 1
    for (int rl = 0; rl < 2; ++rl) {
        const int y  = yb * 2 + rl;
        const int ym = (y > 0) ? y - 1 : 0;
        const int yp = (y < 255) ? y + 1 : 255;
        __syncthreads();                  // smem free (prev row consumed)
        #pragma unroll
        for (int j = 0; j < 8; ++j) {
            const int slot = tid + 256 * j;
            const int rowid = slot >> 6, col4 = slot & 63;
            const int c = rowid >> 2, sel = rowid & 3;
            const int sy = (sel == 0) ? ym : ((sel == 2) ? yp : y);
            const float* src = ((sel == 3) ? img : temp)
                             + ((size_t)(b * K_ + c) * HW + sy * W_ + col4 * 4);
            const float4 v = *(const float4*)src;
            *(float4*)&smem[(c * 4 + sel) * 256 + col4 * 4] = v;
        }
        __syncthreads();

        const int x = tid;
        const int xm = (x > 0) ? x - 1 : 0;
        const int xp = (x < 255) ? x + 1 : 255;
        float Sxx = 0.f, Sxy = 0.f, Syy = 0.f;
        unsigned int imgp[4] = {0, 0, 0, 0};
        unsigned int tgp[12];
        #pragma unroll
        for (int i = 0; i < 12; ++i) tgp[i] = 0u;
        #pragma unroll
        for (int c = 0; c < 8; ++c) {
            const float* R = &smem[c * 1024];
            const float gx = 0.5f * (R[256 + xp] - R[256 + xm]);
            const float gy = 0.5f * (R[512 + x] - R[x]);
            const float tc = R[256 + x];
            const float iv = R[768 + x];
            Sxx += gx * gx; Sxy += gx * gy; Syy += gy * gy;
            const int sh = (c & 1) * 16;
            imgp[c >> 1]     |= ((unsigned int)f2bf(iv)) << sh;
            tgp[c >> 1]      |= ((unsigned int)f2bf(tc)) << sh;
            tgp[4 + (c >> 1)]|= ((unsigned int)f2bf(gx)) << sh;
            tgp[8 + (c >> 1)]|= ((unsigned int)f2bf(gy)) << sh;
        }
        // publish imgT (write-through 8B stores)
        {
            const size_t gpx = (size_t)b * HW + (size_t)y * W_ + x;
            unsigned long long* ip = (unsigned long long*)(imgT + gpx);
            cstoreu8(ip,     ((unsigned long long)imgp[1] << 32) | imgp[0]);
            cstoreu8(ip + 1, ((unsigned long long)imgp[3] << 32) | imgp[2]);
        }
        rT[rl]  = make_uint4(tgp[0], tgp[1], tgp[2],  tgp[3]);
        rGX[rl] = make_uint4(tgp[4], tgp[5], tgp[6],  tgp[7]);
        rGY[rl] = make_uint4(tgp[8], tgp[9], tgp[10], tgp[11]);
        __syncthreads();                  // rows consumed; reuse smem

        // ---- 15 row-moments ----
        {
            const float X = (float)x - 127.5f;
            const float X2 = X * X;
            const float Xp[5] = {1.f, X, X2, X2 * X, X2 * X2};
            #pragma unroll
            for (int n = 0; n < 5; ++n) {
                smem[n * 256 + tid]        = Sxx * Xp[n];
                smem[(5 + n) * 256 + tid]  = Sxy * Xp[n];
                smem[(10 + n) * 256 + tid] = Syy * Xp[n];
            }
        }
        __syncthreads();
        {
            const int e = tid >> 5, l = tid & 31;
            float v = 0.f;
            #pragma unroll
            for (int j = 0; j < 8; ++j) v += smem[e * 256 + l + 32 * j];
            v = half_reduce(v);
            if (l == 0) s15[e] = v;
        }
        if (tid < 224) {
            const int e = 8 + (tid >> 5), l = tid & 31;
            float v = 0.f;
            #pragma unroll
            for (int j = 0; j < 8; ++j) v += smem[e * 256 + l + 32 * j];
            v = half_reduce(v);
            if (l == 0) s15[e] = v;
        }
        __syncthreads();

        // ---- 36 upper-tri Gram entries for this row (coherent f64) ----
        if (tid < 36) {
            const int aC[8]  = {1, 1, 1, 0, 0, 0, -1, -1};
            const int aNX[8] = {1, 0, 0, 0, 0, 0,  2,  1};
            const int aNY[8] = {0, 1, 0, 0, 0, 0,  0,  1};
            const int bC[8]  = {0, 0, 0, 1, 1, 1, -1, -1};
            const int bNX[8] = {0, 0, 0, 1, 0, 0,  1,  0};
            const int bNY[8] = {0, 0, 0, 0, 1, 0,  1,  2};
            const double Yd = (double)((float)y - 127.5f);
            const double Yp2 = Yd * Yd;
            const double Ypw[5] = {1.0, Yd, Yp2, Yp2 * Yd, Yp2 * Yp2};
            int p = 0, rem = tid;
            while (rem >= 8 - p) { rem -= 8 - p; ++p; }
            const int q = p + rem;
            double g = 0.0;
            const int ac = aC[p] * aC[q];
            if (ac) g += ac * Ypw[aNY[p] + aNY[q]] * (double)s15[aNX[p] + aNX[q]];
            const int ab1 = aC[p] * bC[q];
            if (ab1) g += ab1 * Ypw[aNY[p] + bNY[q]] * (double)s15[5 + aNX[p] + bNX[q]];
            const int ab2 = bC[p] * aC[q];
            if (ab2) g += ab2 * Ypw[bNY[p] + aNY[q]] * (double)s15[5 + bNX[p] + aNX[q]];
            const int bc = bC[p] * bC[q];
            if (bc) g += bc * Ypw[bNY[p] + bNY[q]] * (double)s15[10 + bNX[p] + bNX[q]];
            cstored(&gramP[((size_t)b * 36 + tid) * 256 + y], g);
        }
    }

    // ---- prep barrier: all 128 blocks of batch published imgT + gramP ----
    asm volatile("s_waitcnt vmcnt(0)" ::: "memory");
    __syncthreads();
    if (tid == 0) {
        __hip_atomic_fetch_add(&bbar[(40 + part) * 32], 1u,
                               __ATOMIC_RELAXED, __HIP_MEMORY_SCOPE_AGENT);
        wait_sum4(&bbar[40 * 32], 128u);
    }
    __syncthreads();

    // ========================= ITERATION phase =============================
    for (int it = 0; it < mi; ++it) {
        if (it > 0) {
            if (tid == 0) {
                wait_sum4(&bbar[(it - 1) * 4 * 32], 128u);
                if (it == 1) wait_count(&bbar[44 * 32], 1u);
            }
            __syncthreads();
            if (it == 1 && tid < 64) sh_invH[tid] = cloadd(&invHg[b * 64 + tid]);
            {
                const float* sR = ((it & 1) ? sP0 : sP1) + b * 1024;
                const int e = tid >> 5, l = tid & 31;
                float v = cloadf(&sR[e * 128 + l])      + cloadf(&sR[e * 128 + 32 + l])
                        + cloadf(&sR[e * 128 + 64 + l]) + cloadf(&sR[e * 128 + 96 + l]);
                v = half_reduce(v);
                if (l == 0) s8[e] = v;
            }
            __syncthreads();
            if (tid < 8) {
                double nrm2 = 0.0;
                #pragma unroll
                for (int k2 = 0; k2 < 8; ++k2) {
                    const double d = sh_pd[8 + k2];
                    nrm2 += d * d;
                }
                double dpn = 0.0;
                if (tid < 6) {
                    #pragma unroll
                    for (int k2 = 0; k2 < 8; ++k2)
                        dpn += sh_invH[tid * 8 + k2] * (double)s8[k2];
                }
                const double dp2 = (sqrt(nrm2) > 1e-3) ? dpn : 0.0;
                const double pnew = sh_pd[tid] - dp2;
                sh_pd[tid]     = pnew;
                sh_pd[8 + tid] = dp2;
            }
            __syncthreads();
        } else {
            if (tid < 8) {
                sh_pd[tid]     = (double)init_param[b * 8 + tid];
                sh_pd[8 + tid] = 1.0;
            }
            __syncthreads();
        }

        const float h00 = 1.f + (float)sh_pd[0], h01 = (float)sh_pd[1], h02 = (float)sh_pd[2];
        const float h10 = (float)sh_pd[3], h11 = 1.f + (float)sh_pd[4], h12 = (float)sh_pd[5];
        const float h20 = (float)sh_pd[6], h21 = (float)sh_pd[7];

        // ---- pixel phase: 2 px/thread (same rows the thread prepped) ----
        float aa[8];
        #pragma unroll
        for (int e = 0; e < 8; ++e) aa[e] = 0.f;
        #pragma unroll
        for (int sub = 0; sub < 2; ++sub) {
            pixel_accum(imgT, rT[sub], rGX[sub], rGY[sub], b,
                        tid, yb * 2 + sub,
                        h00, h01, h02, h10, h11, h12, h20, h21, aa);
        }

        // ---- block reduce (red overlays smem) -> 8 coherent partials ----
        float* red = smem;
        #pragma unroll
        for (int e = 0; e < 8; ++e) red[e * 256 + tid] = aa[e];
        __syncthreads();
        {
            const int e = tid >> 5, l = tid & 31;
            float v = 0.f;
            #pragma unroll
            for (int j = 0; j < 8; ++j) v += red[e * 256 + l + 32 * j];
            v = half_reduce(v);
            if (l == 0) {
                float* sW = (it & 1) ? sP1 : sP0;
                cstoref(&sW[b * 1024 + e * 128 + yb], v);
            }
        }

        // ---- arrive (split counter) ----
        asm volatile("s_waitcnt vmcnt(0)" ::: "memory");
        __syncthreads();
        if (tid == 0)
            __hip_atomic_fetch_add(&bbar[(it * 4 + part) * 32], 1u,
                                   __ATOMIC_RELAXED, __HIP_MEMORY_SCOPE_AGENT);

        // ---- iter 0, yb==0: Gram reduce + f64 Gauss-Jordan, publish invH ----
        if (it == 0 && yb == 0) {
            if (tid < 144) {
                const int e = tid >> 2, q = tid & 3;
                const double* gp = gramP + ((size_t)b * 36 + e) * 256 + q * 64;
                double acc = 0.0;
                #pragma unroll 8
                for (int i = 0; i < 64; ++i) acc += cloadd(&gp[i]);
                gpart[tid] = acc;
            }
            __syncthreads();
            const int i = tid >> 3, j = tid & 7;
            if (tid < 64) {
                const int pp = min(i, j), qq = max(i, j);
                const int tri = 8 * pp - (pp * (pp - 1)) / 2 + (qq - pp);
                shA[tid] = gpart[tri * 4] + gpart[tri * 4 + 1]
                         + gpart[tri * 4 + 2] + gpart[tri * 4 + 3];
                shB[tid] = (i == j) ? 1.0 : 0.0;
            }
            __syncthreads();
            for (int k = 0; k < 8; ++k) {
                const double piv = shA[k * 8 + k];
                __syncthreads();
                if (tid < 64 && i == k) { shA[tid] /= piv; shB[tid] /= piv; }
                __syncthreads();
                double f = 0, ak = 0, bk = 0;
                if (tid < 64) { f = shA[i * 8 + k]; ak = shA[k * 8 + j]; bk = shB[k * 8 + j]; }
                __syncthreads();
                if (tid < 64 && i != k) { shA[tid] -= f * ak; shB[tid] -= f * bk; }
                __syncthreads();
            }
            if (tid < 64) cstored(&invHg[b * 64 + tid], shB[tid]);
            asm volatile("s_waitcnt vmcnt(0)" ::: "memory");
            __syncthreads();
            if (tid == 0)
                __hip_atomic_fetch_add(&bbar[44 * 32], 1u,
                                       __ATOMIC_RELAXED, __HIP_MEMORY_SCOPE_AGENT);
        }
    }

    // ========================= OUTPUT phase ================================
    if (yb != 0) return;                  // 8 blocks, one per batch
    if (mi <= 0) {
        if (tid < 8) out[b * 8 + tid] = init_param[b * 8 + tid];
        if (tid < 9) {
            float v = (tid < 8) ? init_param[b * 8 + tid] : 0.f;
            if (tid == 0 || tid == 4 || tid == 8) v += 1.f;
            out[64 + b * 9 + tid] = v;
        }
        return;
    }
    if (tid == 0) wait_sum4(&bbar[(mi - 1) * 4 * 32], 128u);
    __syncthreads();
    // mi==1: iter-1 recon never ran, but this block computed invHg itself
    if (mi == 1 && tid < 64) sh_invH[tid] = cloadd(&invHg[b * 64 + tid]);
    {
        const float* sb = (((mi - 1) & 1) ? sP1 : sP0) + b * 1024;
        const int e = tid >> 5, l = tid & 31;
        float v = cloadf(&sb[e * 128 + l])      + cloadf(&sb[e * 128 + 32 + l])
                + cloadf(&sb[e * 128 + 64 + l]) + cloadf(&sb[e * 128 + 96 + l]);
        v = half_reduce(v);
        if (l == 0) s8[e] = v;
    }
    __syncthreads();
    if (tid < 8) {
        double nrm2 = 0.0;
        #pragma unroll
        for (int k2 = 0; k2 < 8; ++k2) {
            const double d = sh_pd[8 + k2];     // dp of last iteration
            nrm2 += d * d;
        }
        double dpn = 0.0;
        if (tid < 6) {
            #pragma unroll
            for (int k2 = 0; k2 < 8; ++k2)
                dpn += sh_invH[tid * 8 + k2] * (double)s8[k2];
        }
        const double dp2 = (sqrt(nrm2) > 1e-3) ? dpn : 0.0;
        const float pf = (float)(sh_pd[tid] - dp2);
        sh_pf[tid] = pf;
        out[b * 8 + tid] = pf;
    }
    __syncthreads();
    if (tid < 9) {
        float v2 = (tid < 8) ? sh_pf[tid] : 0.f;
        if (tid == 0 || tid == 4 || tid == 8) v2 += 1.f;
        out[64 + b * 9 + tid] = v2;
    }
}

extern "C" void kernel_launch(void* const* d_in, const int* in_sizes, int n_in,
                              void* d_out, int out_size, void* d_ws, size_t ws_size,
                              hipStream_t stream) {
    const float* img        = (const float*)d_in[0];
    const float* temp       = (const float*)d_in[1];
    const float* init_param = (const float*)d_in[2];
    const int*   max_itr    = (const int*)d_in[3];
    float* out = (float*)d_out;

    char* w = (char*)d_ws;
    double* gramP = (double*)w;                        // 8*36*256 d = 576 KB
    double* invHg = gramP + 73728;                     // 512 d = 4 KB
    float*  sP0   = (float*)(invHg + 512);             // 8192 f = 32 KB
    float*  sP1   = sP0 + 8192;                        // 32 KB
    unsigned int* bar = (unsigned int*)(sP1 + 8192);   // 512 x 128 B = 64 KB
    uint4* imgT   = (uint4*)(w + 1048576);             // 8.39 MB (bf16 x8 / px)

    zero_bar_kernel<<<1, 512, 0, stream>>>(bar);
    // residency by capacity: grid 1024 == 256 CU x 4; LDS ~35 KB -> 4/CU,
    // VGPR <= 64 (slim pixel path) -> not the limiter.
    fused_kernel<<<NBLK, 256, 0, stream>>>(img, temp, imgT, gramP, invHg,
                                           init_param, sP0, sP1, bar,
                                           max_itr, out);
}

// Round 9
// 209.725 us; speedup vs baseline: 1.2329x; 1.2116x over previous
//
#include <hip/hip_runtime.h>
#include <hip/hip_bf16.h>

#define B_ 8
#define K_ 8
#define H_ 256
#define W_ 256
#define HW (H_*W_)

// ---------------------------------------------------------------------------
// helpers
// ---------------------------------------------------------------------------
__device__ __forceinline__ unsigned short f2bf(float f) {
    __hip_bfloat16 h = __float2bfloat16(f);  // RNE
    return *reinterpret_cast<unsigned short*>(&h);
}
// extract bf16 channel c (elem 2k in low 16 bits, 2k+1 in high) as f32
__device__ __forceinline__ float bfex(uint4 u, int c) {
    const unsigned int w = (&u.x)[c >> 1];
    return __uint_as_float((c & 1) ? (w & 0xffff0000u) : (w << 16));
}
// sum within each 32-lane half of a wave; result valid in lanes 0 and 32
__device__ __forceinline__ float half_reduce(float v) {
    v += __shfl_down(v, 16, 64);
    v += __shfl_down(v, 8, 64);
    v += __shfl_down(v, 4, 64);
    v += __shfl_down(v, 2, 64);
    v += __shfl_down(v, 1, 64);
    return v;
}
// full 64-lane wave reduce; result valid in lane 0
__device__ __forceinline__ float wave_reduce(float v) {
    v += __shfl_down(v, 32, 64);
    v += __shfl_down(v, 16, 64);
    v += __shfl_down(v, 8, 64);
    v += __shfl_down(v, 4, 64);
    v += __shfl_down(v, 2, 64);
    v += __shfl_down(v, 1, 64);
    return v;
}
// fine-grained coherent (cache-bypassing) accesses — NO L2 fences anywhere
__device__ __forceinline__ void cstoref(float* p, float v) {
    __hip_atomic_store(p, v, __ATOMIC_RELAXED, __HIP_MEMORY_SCOPE_AGENT);
}
__device__ __forceinline__ float cloadf(const float* p) {
    return __hip_atomic_load((float*)p, __ATOMIC_RELAXED, __HIP_MEMORY_SCOPE_AGENT);
}
__device__ __forceinline__ void cstored(double* p, double v) {
    __hip_atomic_store(p, v, __ATOMIC_RELAXED, __HIP_MEMORY_SCOPE_AGENT);
}
__device__ __forceinline__ double cloadd(const double* p) {
    return __hip_atomic_load((double*)p, __ATOMIC_RELAXED, __HIP_MEMORY_SCOPE_AGENT);
}
__device__ __forceinline__ void cstoreu8(unsigned long long* p, unsigned long long v) {
    __hip_atomic_store(p, v, __ATOMIC_RELAXED, __HIP_MEMORY_SCOPE_AGENT);
}
__device__ __forceinline__ unsigned int cloadu(const unsigned int* p) {
    return __hip_atomic_load((unsigned int*)p, __ATOMIC_RELAXED, __HIP_MEMORY_SCOPE_AGENT);
}
// TIGHT-bounded spin (leader thread only): ~10 ms worst case — a broken
// barrier becomes a fast wrong-answer-with-counters, never a hang.
__device__ __forceinline__ void wait_count(unsigned int* p, unsigned int target) {
    for (int i = 0; i < 20000; ++i) {
        if (cloadu(p) >= target) return;
        __builtin_amdgcn_s_sleep(1);
    }
}

// per-pixel warp + bilinear + residual; TG fragment comes from registers.
// Register-slim (bfex at use) — bit-identical arithmetic to the array form.
__device__ __forceinline__ void pixel_accum(
    const uint4* __restrict__ imgT,
    const uint4 t0, const uint4 g0, const uint4 g1,
    int b, int x, int y,
    float h00, float h01, float h02, float h10, float h11, float h12,
    float h20, float h21, float* aa) {
    const float X = (float)x - 127.5f, Y = (float)y - 127.5f;
    const float zw = h20 * X + h21 * Y + 1.f;
    const float Xw = (h00 * X + h01 * Y + h02) / zw + 127.5f;
    const float Yw = (h10 * X + h11 * Y + h12) / zw + 127.5f;
    const float NLO = -1.f + 2.f / 256.f, NHI = 1.f - 2.f / 256.f;
    const float xn = Xw / 127.5f - 1.f, yn = Yw / 127.5f - 1.f;
    const float m = (xn > NLO && xn < NHI && yn > NLO && yn < NHI) ? 1.f : 0.f;

    const float x0f = floorf(Xw), y0f = floorf(Yw);
    const float fx = Xw - x0f, fy = Yw - y0f;
    const float x1f = x0f + 1.f, y1f = y0f + 1.f;
    const bool vx0 = (x0f >= 0.f) && (x0f <= 255.f);
    const bool vx1 = (x1f >= 0.f) && (x1f <= 255.f);
    const bool vy0 = (y0f >= 0.f) && (y0f <= 255.f);
    const bool vy1 = (y1f >= 0.f) && (y1f <= 255.f);
    const int xi0 = (int)fminf(fmaxf(x0f, 0.f), 255.f);
    const int xi1 = (int)fminf(fmaxf(x1f, 0.f), 255.f);
    const int yi0 = (int)fminf(fmaxf(y0f, 0.f), 255.f);
    const int yi1 = (int)fminf(fmaxf(y1f, 0.f), 255.f);
    const int i00 = yi0 * W_ + xi0, i01 = yi0 * W_ + xi1;
    const int i10 = yi1 * W_ + xi0, i11 = yi1 * W_ + xi1;
    const float w00 = ((vx0 && vy0) ? 1.f : 0.f) * (1.f - fx) * (1.f - fy);
    const float w01 = ((vx1 && vy0) ? 1.f : 0.f) * fx * (1.f - fy);
    const float w10 = ((vx0 && vy1) ? 1.f : 0.f) * (1.f - fx) * fy;
    const float w11 = ((vx1 && vy1) ? 1.f : 0.f) * fx * fy;

    const int base = b * HW;
    const uint4 u00 = imgT[base + i00], u01 = imgT[base + i01];
    const uint4 u10 = imgT[base + i10], u11 = imgT[base + i11];

    float vx = 0.f, vy = 0.f;
    #pragma unroll
    for (int c = 0; c < 8; ++c) {
        const float Q = w00 * bfex(u00, c) + w01 * bfex(u01, c)
                      + w10 * bfex(u10, c) + w11 * bfex(u11, c);
        const float r = Q - bfex(t0, c) * m;
        vx += bfex(g0, c) * r;
        vy += bfex(g1, c) * r;
    }
    const float t0a = X * vx, t4a = Y * vy;
    const float cc = t0a + t4a;
    aa[0] += t0a;      aa[1] += Y * vx;  aa[2] += vx;
    aa[3] += X * vy;   aa[4] += t4a;     aa[5] += vy;
    aa[6] -= X * cc;   aa[7] -= Y * cc;
}

// ---------------------------------------------------------------------------
// zero the 128 barrier counters (workspace is poisoned between runs).
// ---------------------------------------------------------------------------
__global__ void zero_bar_kernel(unsigned int* __restrict__ bar) {
    bar[threadIdx.x * 32] = 0u;   // 8 batches x 16 slots, one counter per 128B
}

// ---------------------------------------------------------------------------
// fully fused: prep + 10 iterations + inversion + output in ONE kernel,
// built on the round-3 engine (the proven-fastest iteration structure):
// 512 blocks x 256 thr, __launch_bounds__(256,2), 4 px/thread, 64 single-
// counter arrivals/batch. LDS kept ~11 KB (the config where the allocator
// used 100 VGPR; every 32-64KB-LDS fused variant clamped to 60-64 & slowed).
//
// Prep is LDS-FREE: thread x of block (b, yb) owns pixels (x, 4yb..4yb+3);
// per channel it loads the 6 stencil values straight from global (rows are
// contiguous -> coalesced; L2 absorbs the 3x row re-reads), computes
// gx/gy/tc/iv bit-identically, packs TG DIRECTLY into iteration registers
// (TG never touches memory). imgT published with cache-bypassing stores
// (pattern proven rounds 5/7/8). 15 row-moments via wave shuffles + 60-float
// LDS; 36 Gram entries/row published coherent f64.
//
// Barriers (proven R3/R5 scheme): slots per batch: it 0..9, prep 10, invH 11;
// bar[(b*16+slot)*32]. invH computed once per batch (yb==0) during iter 0,
// published slot 11; all blocks load it at iter 1. No L2 fences anywhere.
// ---------------------------------------------------------------------------
__global__ __launch_bounds__(256, 2) void fused_kernel(
    const float* __restrict__ img, const float* __restrict__ temp,
    uint4* __restrict__ imgT, double* __restrict__ gramP,
    double* __restrict__ invHg, const float* __restrict__ init_param,
    float* __restrict__ sP0, float* __restrict__ sP1,
    unsigned int* __restrict__ bar,
    const int* __restrict__ max_itr, float* __restrict__ out) {
    __shared__ float red[2048];       // 8 KB iteration reduce
    __shared__ float s15w[4][15];     // per-wave moment partials
    __shared__ float s15[15];
    __shared__ float s8[8];
    __shared__ double sh_invH[64];
    __shared__ double sh_pd[16];      // p (0..7), dp (8..15)
    __shared__ float sh_pf[8];
    __shared__ double gpart[144];
    __shared__ double shA[64], shB[64];

    const int tid = threadIdx.x;          // 0..255 == pixel x
    const int b   = blockIdx.x & 7;
    const int yb  = blockIdx.x >> 3;      // 0..63, rows 4*yb..4*yb+3
    const int mi_raw = *max_itr;
    const int mi = (mi_raw > 10) ? 10 : mi_raw;

    // ================= PREP phase (LDS-free, TG straight to registers) =====
    uint4 rT[4], rGX[4], rGY[4];
    {
        const int x  = tid;
        const int xm = (x > 0) ? x - 1 : 0;
        const int xp = (x < 255) ? x + 1 : 255;
        const float X = (float)x - 127.5f;
        const float X2 = X * X;
        const float Xp[5] = {1.f, X, X2, X2 * X, X2 * X2};
        const float* tb = temp + (size_t)(b * K_) * HW;
        const float* ib = img  + (size_t)(b * K_) * HW;
        const int wid = tid >> 6, lane = tid & 63;

        #pragma unroll 1
        for (int rl = 0; rl < 4; ++rl) {
            const int y  = yb * 4 + rl;
            const int ym = (y > 0) ? y - 1 : 0;
            const int yp = (y < 255) ? y + 1 : 255;
            const int yo = y * W_, ymo = ym * W_, ypo = yp * W_;
            float Sxx = 0.f, Sxy = 0.f, Syy = 0.f;
            unsigned int imgp[4] = {0, 0, 0, 0};
            unsigned int tgp[12];
            #pragma unroll
            for (int i = 0; i < 12; ++i) tgp[i] = 0u;
            #pragma unroll
            for (int c = 0; c < 8; ++c) {
                const float* R = tb + (size_t)c * HW;
                const float tc   = R[yo + x];
                const float t_xm = R[yo + xm];
                const float t_xp = R[yo + xp];
                const float t_ym = R[ymo + x];
                const float t_yp = R[ypo + x];
                const float iv   = ib[(size_t)c * HW + yo + x];
                const float gx = 0.5f * (t_xp - t_xm);
                const float gy = 0.5f * (t_yp - t_ym);
                Sxx += gx * gx; Sxy += gx * gy; Syy += gy * gy;
                const int sh = (c & 1) * 16;
                imgp[c >> 1]     |= ((unsigned int)f2bf(iv)) << sh;
                tgp[c >> 1]      |= ((unsigned int)f2bf(tc)) << sh;
                tgp[4 + (c >> 1)]|= ((unsigned int)f2bf(gx)) << sh;
                tgp[8 + (c >> 1)]|= ((unsigned int)f2bf(gy)) << sh;
            }
            // publish imgT (write-through 8B stores; pattern proven x3 rounds)
            {
                const size_t gpx = (size_t)b * HW + (size_t)yo + x;
                unsigned long long* ip = (unsigned long long*)(imgT + gpx);
                cstoreu8(ip,     ((unsigned long long)imgp[1] << 32) | imgp[0]);
                cstoreu8(ip + 1, ((unsigned long long)imgp[3] << 32) | imgp[2]);
            }
            rT[rl]  = make_uint4(tgp[0], tgp[1], tgp[2],  tgp[3]);
            rGX[rl] = make_uint4(tgp[4], tgp[5], tgp[6],  tgp[7]);
            rGY[rl] = make_uint4(tgp[8], tgp[9], tgp[10], tgp[11]);

            // ---- 15 row-moments via wave shuffles (no big LDS buffer) ----
            #pragma unroll
            for (int e = 0; e < 15; ++e) {
                const float S = (e < 5) ? Sxx : ((e < 10) ? Sxy : Syy);
                float v = wave_reduce(S * Xp[(e < 5) ? e : ((e < 10) ? e - 5 : e - 10)]);
                if (lane == 0) s15w[wid][e] = v;
            }
            __syncthreads();
            if (tid < 15)
                s15[tid] = s15w[0][tid] + s15w[1][tid]
                         + s15w[2][tid] + s15w[3][tid];
            __syncthreads();

            // ---- 36 upper-tri Gram entries for this row (coherent f64) ----
            if (tid < 36) {
                const int aC[8]  = {1, 1, 1, 0, 0, 0, -1, -1};
                const int aNX[8] = {1, 0, 0, 0, 0, 0,  2,  1};
                const int aNY[8] = {0, 1, 0, 0, 0, 0,  0,  1};
                const int bC[8]  = {0, 0, 0, 1, 1, 1, -1, -1};
                const int bNX[8] = {0, 0, 0, 1, 0, 0,  1,  0};
                const int bNY[8] = {0, 0, 0, 0, 1, 0,  1,  2};
                const double Yd = (double)((float)y - 127.5f);
                const double Yp2 = Yd * Yd;
                const double Ypw[5] = {1.0, Yd, Yp2, Yp2 * Yd, Yp2 * Yp2};
                int p = 0, rem = tid;
                while (rem >= 8 - p) { rem -= 8 - p; ++p; }
                const int q = p + rem;
                double g = 0.0;
                const int ac = aC[p] * aC[q];
                if (ac) g += ac * Ypw[aNY[p] + aNY[q]] * (double)s15[aNX[p] + aNX[q]];
                const int ab1 = aC[p] * bC[q];
                if (ab1) g += ab1 * Ypw[aNY[p] + bNY[q]] * (double)s15[5 + aNX[p] + bNX[q]];
                const int ab2 = bC[p] * aC[q];
                if (ab2) g += ab2 * Ypw[bNY[p] + aNY[q]] * (double)s15[5 + bNX[p] + aNX[q]];
                const int bc = bC[p] * bC[q];
                if (bc) g += bc * Ypw[bNY[p] + bNY[q]] * (double)s15[10 + bNX[p] + bNX[q]];
                cstored(&gramP[((size_t)b * 36 + tid) * 256 + y], g);
            }
        }
    }

    // ---- prep barrier: all 64 blocks of batch published imgT + gramP ----
    asm volatile("s_waitcnt vmcnt(0)" ::: "memory");
    __syncthreads();
    if (tid == 0) {
        __hip_atomic_fetch_add(&bar[(b * 16 + 10) * 32], 1u,
                               __ATOMIC_RELAXED, __HIP_MEMORY_SCOPE_AGENT);
        wait_count(&bar[(b * 16 + 10) * 32], 64u);
    }
    __syncthreads();

    // ========================= ITERATION phase (R3 engine) =================
    for (int it = 0; it < mi; ++it) {
        if (it > 0) {
            if (tid == 0) {
                wait_count(&bar[(b * 16 + (it - 1)) * 32], 64u);
                if (it == 1) wait_count(&bar[(b * 16 + 11) * 32], 1u);
            }
            __syncthreads();
            if (it == 1 && tid < 64) sh_invH[tid] = cloadd(&invHg[b * 64 + tid]);
            {
                const float* sR = ((it & 1) ? sP0 : sP1) + b * 512;
                const int e = tid >> 5, l = tid & 31;
                float v = cloadf(&sR[e * 64 + l]) + cloadf(&sR[e * 64 + 32 + l]);
                v = half_reduce(v);
                if (l == 0) s8[e] = v;
            }
            __syncthreads();
            if (tid < 8) {
                double nrm2 = 0.0;
                #pragma unroll
                for (int k2 = 0; k2 < 8; ++k2) {
                    const double d = sh_pd[8 + k2];
                    nrm2 += d * d;
                }
                double dpn = 0.0;
                if (tid < 6) {
                    #pragma unroll
                    for (int k2 = 0; k2 < 8; ++k2)
                        dpn += sh_invH[tid * 8 + k2] * (double)s8[k2];
                }
                const double dp2 = (sqrt(nrm2) > 1e-3) ? dpn : 0.0;
                const double pnew = sh_pd[tid] - dp2;
                sh_pd[tid]     = pnew;
                sh_pd[8 + tid] = dp2;
            }
            __syncthreads();
        } else {
            if (tid < 8) {
                sh_pd[tid]     = (double)init_param[b * 8 + tid];
                sh_pd[8 + tid] = 1.0;
            }
            __syncthreads();
        }

        const float h00 = 1.f + (float)sh_pd[0], h01 = (float)sh_pd[1], h02 = (float)sh_pd[2];
        const float h10 = (float)sh_pd[3], h11 = 1.f + (float)sh_pd[4], h12 = (float)sh_pd[5];
        const float h20 = (float)sh_pd[6], h21 = (float)sh_pd[7];

        // ---- pixel phase: 4 px/thread fully unrolled (16 gathers) ----
        float aa[8];
        #pragma unroll
        for (int e = 0; e < 8; ++e) aa[e] = 0.f;
        #pragma unroll
        for (int sub = 0; sub < 4; ++sub) {
            pixel_accum(imgT, rT[sub], rGX[sub], rGY[sub], b, tid, yb * 4 + sub,
                        h00, h01, h02, h10, h11, h12, h20, h21, aa);
        }

        // ---- block reduce -> 8 coherent partial stores per block ----
        #pragma unroll
        for (int e = 0; e < 8; ++e) red[e * 256 + tid] = aa[e];
        __syncthreads();
        {
            const int e = tid >> 5, l = tid & 31;
            float v = 0.f;
            #pragma unroll
            for (int j = 0; j < 8; ++j) v += red[e * 256 + l + 32 * j];
            v = half_reduce(v);
            if (l == 0) {
                float* sW = (it & 1) ? sP1 : sP0;
                cstoref(&sW[b * 512 + e * 64 + yb], v);
            }
        }

        // ---- arrive ----
        asm volatile("s_waitcnt vmcnt(0)" ::: "memory");
        __syncthreads();
        if (tid == 0)
            __hip_atomic_fetch_add(&bar[(b * 16 + it) * 32], 1u,
                                   __ATOMIC_RELAXED, __HIP_MEMORY_SCOPE_AGENT);

        // ---- iter 0, yb==0: Gram reduce + f64 Gauss-Jordan, publish invH ----
        if (it == 0 && yb == 0) {
            if (tid < 144) {
                const int e = tid >> 2, q = tid & 3;
                const double* gp = gramP + ((size_t)b * 36 + e) * 256 + q * 64;
                double acc = 0.0;
                #pragma unroll 8
                for (int i = 0; i < 64; ++i) acc += cloadd(&gp[i]);
                gpart[tid] = acc;
            }
            __syncthreads();
            const int i = tid >> 3, j = tid & 7;
            if (tid < 64) {
                const int pp = min(i, j), qq = max(i, j);
                const int tri = 8 * pp - (pp * (pp - 1)) / 2 + (qq - pp);
                shA[tid] = gpart[tri * 4] + gpart[tri * 4 + 1]
                         + gpart[tri * 4 + 2] + gpart[tri * 4 + 3];
                shB[tid] = (i == j) ? 1.0 : 0.0;
            }
            __syncthreads();
            for (int k = 0; k < 8; ++k) {
                const double piv = shA[k * 8 + k];
                __syncthreads();
                if (tid < 64 && i == k) { shA[tid] /= piv; shB[tid] /= piv; }
                __syncthreads();
                double f = 0, ak = 0, bk = 0;
                if (tid < 64) { f = shA[i * 8 + k]; ak = shA[k * 8 + j]; bk = shB[k * 8 + j]; }
                __syncthreads();
                if (tid < 64 && i != k) { shA[tid] -= f * ak; shB[tid] -= f * bk; }
                __syncthreads();
            }
            if (tid < 64) { cstored(&invHg[b * 64 + tid], shB[tid]);
                            sh_invH[tid] = shB[tid]; }   // local stash (mi==1 path)
            asm volatile("s_waitcnt vmcnt(0)" ::: "memory");
            __syncthreads();
            if (tid == 0)
                __hip_atomic_fetch_add(&bar[(b * 16 + 11) * 32], 1u,
                                       __ATOMIC_RELAXED, __HIP_MEMORY_SCOPE_AGENT);
        }
    }

    // ========================= OUTPUT phase ================================
    if (yb != 0) return;                  // 8 blocks, one per batch
    if (mi <= 0) {
        if (tid < 8) out[b * 8 + tid] = init_param[b * 8 + tid];
        if (tid < 9) {
            float v = (tid < 8) ? init_param[b * 8 + tid] : 0.f;
            if (tid == 0 || tid == 4 || tid == 8) v += 1.f;
            out[64 + b * 9 + tid] = v;
        }
        return;
    }
    if (tid == 0) wait_count(&bar[(b * 16 + (mi - 1)) * 32], 64u);
    __syncthreads();
    // sh_invH: stashed at it==0 (mi==1) or loaded at it==1 (mi>=2) — present.
    {
        const float* sb = (((mi - 1) & 1) ? sP1 : sP0) + b * 512;
        const int e = tid >> 5, l = tid & 31;
        float v = cloadf(&sb[e * 64 + l]) + cloadf(&sb[e * 64 + 32 + l]);
        v = half_reduce(v);
        if (l == 0) s8[e] = v;
    }
    __syncthreads();
    if (tid < 8) {
        double nrm2 = 0.0;
        #pragma unroll
        for (int k2 = 0; k2 < 8; ++k2) {
            const double d = sh_pd[8 + k2];     // dp of last iteration
            nrm2 += d * d;
        }
        double dpn = 0.0;
        if (tid < 6) {
            #pragma unroll
            for (int k2 = 0; k2 < 8; ++k2)
                dpn += sh_invH[tid * 8 + k2] * (double)s8[k2];
        }
        const double dp2 = (sqrt(nrm2) > 1e-3) ? dpn : 0.0;
        const float pf = (float)(sh_pd[tid] - dp2);
        sh_pf[tid] = pf;
        out[b * 8 + tid] = pf;
    }
    __syncthreads();
    if (tid < 9) {
        float v2 = (tid < 8) ? sh_pf[tid] : 0.f;
        if (tid == 0 || tid == 4 || tid == 8) v2 += 1.f;
        out[64 + b * 9 + tid] = v2;
    }
}

extern "C" void kernel_launch(void* const* d_in, const int* in_sizes, int n_in,
                              void* d_out, int out_size, void* d_ws, size_t ws_size,
                              hipStream_t stream) {
    const float* img        = (const float*)d_in[0];
    const float* temp       = (const float*)d_in[1];
    const float* init_param = (const float*)d_in[2];
    const int*   max_itr    = (const int*)d_in[3];
    float* out = (float*)d_out;

    char* w = (char*)d_ws;
    double* gramP = (double*)w;                        // 8*36*256 d = 576 KB
    double* invHg = gramP + 73728;                     // 512 d = 4 KB
    float*  sP0   = (float*)(invHg + 512);             // 4096 f = 16 KB
    float*  sP1   = sP0 + 4096;                        // 16 KB
    unsigned int* bar = (unsigned int*)(sP1 + 4096);   // 128 x 128 B = 16 KB
    uint4* imgT   = (uint4*)(w + 1048576);             // 8.39 MB (bf16 x8 / px)

    zero_bar_kernel<<<1, 128, 0, stream>>>(bar);
    // residency by capacity: grid 512 == 256 CU x 2; LDS ~11 KB and any
    // VGPR count <= 256 both allow >= 2 blocks/CU -> all blocks resident.
    fused_kernel<<<512, 256, 0, stream>>>(img, temp, imgT, gramP, invHg,
                                          init_param, sP0, sP1, bar,
                                          max_itr, out);
}

// Round 10
// 161.372 us; speedup vs baseline: 1.6023x; 1.2996x over previous
//
#include <hip/hip_runtime.h>
#include <hip/hip_bf16.h>

#define B_ 8
#define K_ 8
#define H_ 256
#define W_ 256
#define HW (H_*W_)

// ---------------------------------------------------------------------------
// helpers
// ---------------------------------------------------------------------------
__device__ __forceinline__ unsigned short f2bf(float f) {
    __hip_bfloat16 h = __float2bfloat16(f);  // RNE
    return *reinterpret_cast<unsigned short*>(&h);
}
// extract bf16 channel c (elem 2k low 16 bits, 2k+1 high) as f32; c is
// compile-time under #pragma unroll -> pure shift/mask, no unpack arrays.
__device__ __forceinline__ float bfex(uint4 u, int c) {
    const unsigned int w = (&u.x)[c >> 1];
    return __uint_as_float((c & 1) ? (w & 0xffff0000u) : (w << 16));
}
// sum within each 32-lane half of a wave; result valid in lanes 0 and 32
__device__ __forceinline__ float half_reduce(float v) {
    v += __shfl_down(v, 16, 64);
    v += __shfl_down(v, 8, 64);
    v += __shfl_down(v, 4, 64);
    v += __shfl_down(v, 2, 64);
    v += __shfl_down(v, 1, 64);
    return v;
}

// per-pixel warp + bilinear + residual; TG fragment in registers (bfex form)
__device__ __forceinline__ void pixel_accum(
    const uint4* __restrict__ imgT,
    const uint4 t0, const uint4 g0, const uint4 g1,
    int b, int x, int y,
    float h00, float h01, float h02, float h10, float h11, float h12,
    float h20, float h21, float* aa) {
    const float X = (float)x - 127.5f, Y = (float)y - 127.5f;
    const float zw = h20 * X + h21 * Y + 1.f;
    const float Xw = (h00 * X + h01 * Y + h02) / zw + 127.5f;
    const float Yw = (h10 * X + h11 * Y + h12) / zw + 127.5f;
    const float NLO = -1.f + 2.f / 256.f, NHI = 1.f - 2.f / 256.f;
    const float xn = Xw / 127.5f - 1.f, yn = Yw / 127.5f - 1.f;
    const float m = (xn > NLO && xn < NHI && yn > NLO && yn < NHI) ? 1.f : 0.f;

    const float x0f = floorf(Xw), y0f = floorf(Yw);
    const float fx = Xw - x0f, fy = Yw - y0f;
    const float x1f = x0f + 1.f, y1f = y0f + 1.f;
    const bool vx0 = (x0f >= 0.f) && (x0f <= 255.f);
    const bool vx1 = (x1f >= 0.f) && (x1f <= 255.f);
    const bool vy0 = (y0f >= 0.f) && (y0f <= 255.f);
    const bool vy1 = (y1f >= 0.f) && (y1f <= 255.f);
    const int xi0 = (int)fminf(fmaxf(x0f, 0.f), 255.f);
    const int xi1 = (int)fminf(fmaxf(x1f, 0.f), 255.f);
    const int yi0 = (int)fminf(fmaxf(y0f, 0.f), 255.f);
    const int yi1 = (int)fminf(fmaxf(y1f, 0.f), 255.f);
    const int i00 = yi0 * W_ + xi0, i01 = yi0 * W_ + xi1;
    const int i10 = yi1 * W_ + xi0, i11 = yi1 * W_ + xi1;
    const float w00 = ((vx0 && vy0) ? 1.f : 0.f) * (1.f - fx) * (1.f - fy);
    const float w01 = ((vx1 && vy0) ? 1.f : 0.f) * fx * (1.f - fy);
    const float w10 = ((vx0 && vy1) ? 1.f : 0.f) * (1.f - fx) * fy;
    const float w11 = ((vx1 && vy1) ? 1.f : 0.f) * fx * fy;

    const int base = b * HW;
    const uint4 u00 = imgT[base + i00], u01 = imgT[base + i01];
    const uint4 u10 = imgT[base + i10], u11 = imgT[base + i11];

    float vx = 0.f, vy = 0.f;
    #pragma unroll
    for (int c = 0; c < 8; ++c) {
        const float Q = w00 * bfex(u00, c) + w01 * bfex(u01, c)
                      + w10 * bfex(u10, c) + w11 * bfex(u11, c);
        const float r = Q - bfex(t0, c) * m;
        vx += bfex(g0, c) * r;
        vy += bfex(g1, c) * r;
    }
    const float t0a = X * vx, t4a = Y * vy;
    const float cc = t0a + t4a;
    aa[0] += t0a;      aa[1] += Y * vx;  aa[2] += vx;
    aa[3] += X * vy;   aa[4] += t4a;     aa[5] += vy;
    aa[6] -= X * cc;   aa[7] -= Y * cc;
}

// ---------------------------------------------------------------------------
// prep: LDS-staged float4 loads (proven ~15 µs at 2048 blocks), planar
// bf16 TG outputs, Gram via 15 row-moments. All PLAIN cached stores —
// dispatch boundaries provide visibility (no coherent-store amplification).
// ---------------------------------------------------------------------------
__global__ __launch_bounds__(256) void prep_kernel(
    const float* __restrict__ img, const float* __restrict__ temp,
    uint4* __restrict__ imgT, uint4* __restrict__ TGt,
    uint4* __restrict__ TGx, uint4* __restrict__ TGy,
    double* __restrict__ gramP) {
    __shared__ float smem[8192];
    __shared__ float s15[15];
    const int b   = blockIdx.x & 7;
    const int y   = blockIdx.x >> 3;
    const int tid = threadIdx.x;
    const int ym = (y > 0) ? y - 1 : 0;
    const int yp = (y < 255) ? y + 1 : 255;

    #pragma unroll
    for (int j = 0; j < 8; ++j) {
        const int slot = tid + 256 * j;
        const int rowid = slot >> 6, col4 = slot & 63;
        const int c = rowid >> 2, sel = rowid & 3;
        const int sy = (sel == 0) ? ym : ((sel == 2) ? yp : y);
        const float* src = ((sel == 3) ? img : temp)
                         + ((size_t)(b * K_ + c) * HW + sy * W_ + col4 * 4);
        const float4 v = *(const float4*)src;
        *(float4*)&smem[(c * 4 + sel) * 256 + col4 * 4] = v;
    }
    __syncthreads();

    const int x = tid;
    const int px = (y << 8) | x;
    const float X = (float)x - 127.5f, Y = (float)y - 127.5f;
    const int xm = (x > 0) ? x - 1 : 0;
    const int xp = (x < 255) ? x + 1 : 255;
    float Sxx = 0.f, Sxy = 0.f, Syy = 0.f;
    unsigned int imgp[4] = {0, 0, 0, 0};
    unsigned int tgp[12];
    #pragma unroll
    for (int i = 0; i < 12; ++i) tgp[i] = 0u;
    #pragma unroll
    for (int c = 0; c < 8; ++c) {
        const float* R = &smem[c * 1024];
        const float gx = 0.5f * (R[256 + xp] - R[256 + xm]);
        const float gy = 0.5f * (R[512 + x] - R[x]);
        const float tc = R[256 + x];
        const float iv = R[768 + x];
        Sxx += gx * gx; Sxy += gx * gy; Syy += gy * gy;
        const int sh = (c & 1) * 16;
        imgp[c >> 1]     |= ((unsigned int)f2bf(iv)) << sh;
        tgp[c >> 1]      |= ((unsigned int)f2bf(tc)) << sh;
        tgp[4 + (c >> 1)]|= ((unsigned int)f2bf(gx)) << sh;
        tgp[8 + (c >> 1)]|= ((unsigned int)f2bf(gy)) << sh;
    }
    const size_t gpx = (size_t)b * HW + px;
    imgT[gpx] = make_uint4(imgp[0], imgp[1], imgp[2], imgp[3]);
    TGt[gpx] = make_uint4(tgp[0], tgp[1], tgp[2],  tgp[3]);
    TGx[gpx] = make_uint4(tgp[4], tgp[5], tgp[6],  tgp[7]);
    TGy[gpx] = make_uint4(tgp[8], tgp[9], tgp[10], tgp[11]);
    __syncthreads();   // rows consumed; reuse smem for the moment reduce

    {
        const float X2 = X * X;
        const float Xp[5] = {1.f, X, X2, X2 * X, X2 * X2};
        #pragma unroll
        for (int n = 0; n < 5; ++n) {
            smem[n * 256 + tid]        = Sxx * Xp[n];
            smem[(5 + n) * 256 + tid]  = Sxy * Xp[n];
            smem[(10 + n) * 256 + tid] = Syy * Xp[n];
        }
    }
    __syncthreads();
    {
        const int e = tid >> 5, l = tid & 31;
        float v = 0.f;
        #pragma unroll
        for (int j = 0; j < 8; ++j) v += smem[e * 256 + l + 32 * j];
        v = half_reduce(v);
        if (l == 0) s15[e] = v;
    }
    if (tid < 224) {
        const int e = 8 + (tid >> 5), l = tid & 31;
        float v = 0.f;
        #pragma unroll
        for (int j = 0; j < 8; ++j) v += smem[e * 256 + l + 32 * j];
        v = half_reduce(v);
        if ((tid & 31) == 0) s15[e] = v;
    }
    __syncthreads();

    if (tid < 36) {
        const int aC[8]  = {1, 1, 1, 0, 0, 0, -1, -1};
        const int aNX[8] = {1, 0, 0, 0, 0, 0,  2,  1};
        const int aNY[8] = {0, 1, 0, 0, 0, 0,  0,  1};
        const int bC[8]  = {0, 0, 0, 1, 1, 1, -1, -1};
        const int bNX[8] = {0, 0, 0, 1, 0, 0,  1,  0};
        const int bNY[8] = {0, 0, 0, 0, 1, 0,  1,  2};
        const double Yd = (double)Y;
        const double Yp2 = Yd * Yd;
        const double Ypw[5] = {1.0, Yd, Yp2, Yp2 * Yd, Yp2 * Yp2};
        int p = 0, rem = tid;
        while (rem >= 8 - p) { rem -= 8 - p; ++p; }
        const int q = p + rem;
        double g = 0.0;
        const int ac = aC[p] * aC[q];
        if (ac) g += ac * Ypw[aNY[p] + aNY[q]] * (double)s15[aNX[p] + aNX[q]];
        const int ab1 = aC[p] * bC[q];
        if (ab1) g += ab1 * Ypw[aNY[p] + bNY[q]] * (double)s15[5 + aNX[p] + bNX[q]];
        const int ab2 = bC[p] * aC[q];
        if (ab2) g += ab2 * Ypw[bNY[p] + aNY[q]] * (double)s15[5 + bNX[p] + aNX[q]];
        const int bc = bC[p] * bC[q];
        if (bc) g += bc * Ypw[bNY[p] + bNY[q]] * (double)s15[10 + bNX[p] + bNX[q]];
        gramP[((size_t)b * 36 + tid) * 256 + y] = g;
    }
}

// ---------------------------------------------------------------------------
// iter k: 2048 blocks (one block per image row; blockIdx%8 = batch -> each
// XCD's round-robin share is one batch, whose imgT (1MB) + TG (3MB) fits its
// private 4MB L2), 256 thr, 1 px/thread -> 8 blocks/CU, up to 32 waves/CU
// (4x the old 512-block engine's latency hiding). On it==0, blocks
// 2048..2055 run the Gram reduce + f64 Gauss-Jordan (invH needed at it==1,
// read across the dispatch boundary). All plain cached loads/stores.
// ---------------------------------------------------------------------------
__global__ __launch_bounds__(256) void iter_kernel(
    const uint4* __restrict__ imgT, const uint4* __restrict__ TGt,
    const uint4* __restrict__ TGx, const uint4* __restrict__ TGy,
    const double* __restrict__ gramP, double* __restrict__ invHg,
    const double* __restrict__ invH, const float* __restrict__ init_param,
    const double* __restrict__ stateR, double* __restrict__ stateW,
    const float* __restrict__ sPrev, float* __restrict__ sNext,
    const int* __restrict__ max_itr, int iter) {
    if (iter >= *max_itr) return;
    __shared__ float red[2048];
    __shared__ float s8[8];
    __shared__ double sh_invH[64];
    __shared__ double sh_pd[16];

    const int tid = threadIdx.x;

    if (iter == 0 && blockIdx.x >= 2048) {
        // ---- inversion for batch b (inside iter0's dispatch) ----
        const int b = blockIdx.x - 2048;
        __shared__ double gpart[144];
        __shared__ double shA[64];
        __shared__ double shB[64];
        if (tid < 144) {
            const int e = tid >> 2, q = tid & 3;
            const double* gp = gramP + ((size_t)b * 36 + e) * 256 + q * 64;
            double acc = 0.0;
            #pragma unroll 8
            for (int i = 0; i < 64; ++i) acc += gp[i];
            gpart[tid] = acc;
        }
        __syncthreads();
        const int i = tid >> 3, j = tid & 7;
        if (tid < 64) {
            const int pp = min(i, j), qq = max(i, j);
            const int tri = 8 * pp - (pp * (pp - 1)) / 2 + (qq - pp);
            shA[tid] = gpart[tri * 4] + gpart[tri * 4 + 1]
                     + gpart[tri * 4 + 2] + gpart[tri * 4 + 3];
            shB[tid] = (i == j) ? 1.0 : 0.0;
        }
        __syncthreads();
        for (int k = 0; k < 8; ++k) {
            const double piv = shA[k * 8 + k];
            __syncthreads();
            if (tid < 64 && i == k) { shA[tid] /= piv; shB[tid] /= piv; }
            __syncthreads();
            double f = 0, ak = 0, bk = 0;
            if (tid < 64) { f = shA[i * 8 + k]; ak = shA[k * 8 + j]; bk = shB[k * 8 + j]; }
            __syncthreads();
            if (tid < 64 && i != k) { shA[tid] -= f * ak; shB[tid] -= f * bk; }
            __syncthreads();
        }
        if (tid < 64) invHg[b * 64 + tid] = shB[tid];
        return;
    }

    const int b  = blockIdx.x & 7;
    const int yb = blockIdx.x >> 3;        // 0..255 == image row

    // ---- stage A: state reconstruction (redundant per block, identical) ----
    if (iter == 0) {
        if (tid < 8) {
            sh_pd[tid]     = (double)init_param[b * 8 + tid];
            sh_pd[8 + tid] = 1.0;
        }
        __syncthreads();
    } else {
        if (tid < 64) sh_invH[tid] = invH[b * 64 + tid];
        {
            const float* sR = sPrev + b * 2048;
            const int e = tid >> 5, l = tid & 31;
            float v = 0.f;
            #pragma unroll
            for (int j = 0; j < 8; ++j) v += sR[e * 256 + l + 32 * j];
            v = half_reduce(v);
            if (l == 0) s8[e] = v;
        }
        __syncthreads();
        if (tid < 8) {
            double nrm2 = 0.0;
            #pragma unroll
            for (int k2 = 0; k2 < 8; ++k2) {
                const double d = stateR[64 + b * 8 + k2];
                nrm2 += d * d;
            }
            double dpn = 0.0;
            if (tid < 6) {
                #pragma unroll
                for (int k2 = 0; k2 < 8; ++k2)
                    dpn += sh_invH[tid * 8 + k2] * (double)s8[k2];
            }
            const double dp2 = (sqrt(nrm2) > 1e-3) ? dpn : 0.0;
            sh_pd[tid]     = stateR[b * 8 + tid] - dp2;
            sh_pd[8 + tid] = dp2;
        }
        __syncthreads();
    }
    if (yb == 0 && tid < 8) {
        stateW[b * 8 + tid]      = sh_pd[tid];
        stateW[64 + b * 8 + tid] = sh_pd[8 + tid];
    }

    const float h00 = 1.f + (float)sh_pd[0], h01 = (float)sh_pd[1], h02 = (float)sh_pd[2];
    const float h10 = (float)sh_pd[3], h11 = 1.f + (float)sh_pd[4], h12 = (float)sh_pd[5];
    const float h20 = (float)sh_pd[6], h21 = (float)sh_pd[7];

    // ---- stage B: 1 px/thread ----
    float aa[8];
    #pragma unroll
    for (int e = 0; e < 8; ++e) aa[e] = 0.f;
    {
        const size_t gpx = (size_t)b * HW + (size_t)yb * W_ + tid;
        const uint4 t0 = TGt[gpx], g0 = TGx[gpx], g1 = TGy[gpx];
        pixel_accum(imgT, t0, g0, g1, b, tid, yb,
                    h00, h01, h02, h10, h11, h12, h20, h21, aa);
    }

    // ---- block reduce -> 8 partials per block (plain stores) ----
    #pragma unroll
    for (int e = 0; e < 8; ++e) red[e * 256 + tid] = aa[e];
    __syncthreads();
    {
        const int e = tid >> 5, l = tid & 31;
        float v = 0.f;
        #pragma unroll
        for (int j = 0; j < 8; ++j) v += red[e * 256 + l + 32 * j];
        v = half_reduce(v);
        if (l == 0) sNext[b * 2048 + e * 256 + yb] = v;
    }
}

// ---------------------------------------------------------------------------
// output: final update (reduce last partials) + write p, H. grid = B_.
// ---------------------------------------------------------------------------
__global__ void output_kernel(const double* __restrict__ invH,
                              const float* __restrict__ init_param,
                              const double* __restrict__ st0,
                              const double* __restrict__ st1,
                              const float* __restrict__ sP0,
                              const float* __restrict__ sP1,
                              const int* __restrict__ max_itr,
                              float* __restrict__ out) {
    const int b   = blockIdx.x;
    const int tid = threadIdx.x;
    const int mi_raw = *max_itr;
    const int mi = (mi_raw > 10) ? 10 : mi_raw;
    if (mi <= 0) {
        if (tid < 8) out[b * 8 + tid] = init_param[b * 8 + tid];
        if (tid < 9) {
            float v = (tid < 8) ? init_param[b * 8 + tid] : 0.f;
            if (tid == 0 || tid == 4 || tid == 8) v += 1.f;
            out[64 + b * 9 + tid] = v;
        }
        return;
    }
    const int pr = (mi - 1) & 1;
    const double* st = pr ? st1 : st0;
    const float*  sP = pr ? sP1 : sP0;
    __shared__ float s8[8];
    __shared__ float sh_pf[8];
    {
        const float* sb = sP + b * 2048;
        const int e = tid >> 5, l = tid & 31;
        float v = 0.f;
        #pragma unroll
        for (int j = 0; j < 8; ++j) v += sb[e * 256 + l + 32 * j];
        v = half_reduce(v);
        if (l == 0) s8[e] = v;
    }
    __syncthreads();
    if (tid < 8) {
        double nrm2 = 0.0;
        #pragma unroll
        for (int k2 = 0; k2 < 8; ++k2) {
            const double d = st[64 + b * 8 + k2];
            nrm2 += d * d;
        }
        double dpn = 0.0;
        if (tid < 6) {
            #pragma unroll
            for (int k2 = 0; k2 < 8; ++k2)
                dpn += invH[b * 64 + tid * 8 + k2] * (double)s8[k2];
        }
        const double dp2 = (sqrt(nrm2) > 1e-3) ? dpn : 0.0;
        const float pf = (float)(st[b * 8 + tid] - dp2);
        sh_pf[tid] = pf;
        out[b * 8 + tid] = pf;
    }
    __syncthreads();
    if (tid < 9) {
        float v2 = (tid < 8) ? sh_pf[tid] : 0.f;
        if (tid == 0 || tid == 4 || tid == 8) v2 += 1.f;
        out[64 + b * 9 + tid] = v2;
    }
}

extern "C" void kernel_launch(void* const* d_in, const int* in_sizes, int n_in,
                              void* d_out, int out_size, void* d_ws, size_t ws_size,
                              hipStream_t stream) {
    const float* img        = (const float*)d_in[0];
    const float* temp       = (const float*)d_in[1];
    const float* init_param = (const float*)d_in[2];
    const int*   max_itr    = (const int*)d_in[3];
    float* out = (float*)d_out;

    char* w = (char*)d_ws;
    double* gramP = (double*)w;                       // 8*36*256 d = 576 KB
    double* st0   = gramP + 73728;                    // 128 d (p + dp)
    double* st1   = st0 + 128;                        // 128 d
    double* invH  = st1 + 128;                        // 512 d
    float*  sP0   = (float*)(invH + 512);             // 8*2048 f = 64 KB
    float*  sP1   = sP0 + 16384;                      // 64 KB
    uint4* imgT   = (uint4*)(w + 1048576);            // 8.39 MB (bf16 x8 / px)
    uint4* TGt    = (uint4*)(w + 1048576 + 8388608);  // planar T / GX / GY
    uint4* TGx    = TGt + (size_t)B_ * HW;
    uint4* TGy    = TGx + (size_t)B_ * HW;

    prep_kernel<<<B_ * H_, 256, 0, stream>>>(img, temp, imgT, TGt, TGx, TGy,
                                             gramP);
    for (int it = 0; it < 10; ++it) {
        const double* stR = (it & 1) ? st0 : st1;
        double*       stW = (it & 1) ? st1 : st0;
        const float*  sR  = (it & 1) ? sP0 : sP1;
        float*        sW  = (it & 1) ? sP1 : sP0;
        const int grid = (it == 0) ? 2056 : 2048;
        iter_kernel<<<grid, 256, 0, stream>>>(imgT, TGt, TGx, TGy, gramP,
                                              invH, invH, init_param,
                                              stR, stW, sR, sW, max_itr, it);
    }
    output_kernel<<<B_, 256, 0, stream>>>(invH, init_param, st0, st1,
                                          sP0, sP1, max_itr, out);
}

// Round 11
// 156.250 us; speedup vs baseline: 1.6548x; 1.0328x over previous
//
#include <hip/hip_runtime.h>
#include <hip/hip_bf16.h>

#define B_ 8
#define K_ 8
#define H_ 256
#define W_ 256
#define HW (H_*W_)

// ---------------------------------------------------------------------------
// helpers
// ---------------------------------------------------------------------------
__device__ __forceinline__ unsigned short f2bf(float f) {
    __hip_bfloat16 h = __float2bfloat16(f);  // RNE
    return *reinterpret_cast<unsigned short*>(&h);
}
// extract bf16 channel c (elem 2k low 16 bits, 2k+1 high) as f32; c is
// compile-time under #pragma unroll -> pure shift/mask, no unpack arrays.
__device__ __forceinline__ float bfex(uint4 u, int c) {
    const unsigned int w = (&u.x)[c >> 1];
    return __uint_as_float((c & 1) ? (w & 0xffff0000u) : (w << 16));
}
// sum within each 32-lane half of a wave; result valid in lanes 0 and 32
__device__ __forceinline__ float half_reduce(float v) {
    v += __shfl_down(v, 16, 64);
    v += __shfl_down(v, 8, 64);
    v += __shfl_down(v, 4, 64);
    v += __shfl_down(v, 2, 64);
    v += __shfl_down(v, 1, 64);
    return v;
}
// fine-grained coherent (cache-bypassing) accesses — NO L2 fences anywhere
__device__ __forceinline__ void cstoref(float* p, float v) {
    __hip_atomic_store(p, v, __ATOMIC_RELAXED, __HIP_MEMORY_SCOPE_AGENT);
}
__device__ __forceinline__ float cloadf(const float* p) {
    return __hip_atomic_load((float*)p, __ATOMIC_RELAXED, __HIP_MEMORY_SCOPE_AGENT);
}
__device__ __forceinline__ void cstored(double* p, double v) {
    __hip_atomic_store(p, v, __ATOMIC_RELAXED, __HIP_MEMORY_SCOPE_AGENT);
}
__device__ __forceinline__ double cloadd(const double* p) {
    return __hip_atomic_load((double*)p, __ATOMIC_RELAXED, __HIP_MEMORY_SCOPE_AGENT);
}
__device__ __forceinline__ void cstoreu(unsigned int* p, unsigned int v) {
    __hip_atomic_store(p, v, __ATOMIC_RELAXED, __HIP_MEMORY_SCOPE_AGENT);
}
__device__ __forceinline__ unsigned int cloadu(const unsigned int* p) {
    return __hip_atomic_load((unsigned int*)p, __ATOMIC_RELAXED, __HIP_MEMORY_SCOPE_AGENT);
}
// bounded single-flag poll (leader thread) — fast-fail, never hangs
__device__ __forceinline__ void wait_count(unsigned int* p, unsigned int target) {
    for (int i = 0; i < 20000; ++i) {
        if (cloadu(p) >= target) return;
        __builtin_amdgcn_s_sleep(1);
    }
}
// wave-parallel 64-flag wait: lanes 0..63 each poll ONE flag (own cacheline,
// stride 16 u32 = 64 B). Writers store flags in parallel (no RMW chain — the
// serialized 64-RMW arrival was ~4.8 µs/iter in the counter-barrier design).
// Bounded; all lanes exit together via uniform __ballot.
__device__ __forceinline__ void wait_flags64(unsigned int* base, int lane) {
    for (int i = 0; i < 20000; ++i) {
        const unsigned int v = cloadu(base + lane * 16);
        if (!__ballot(v == 0u)) return;
        __builtin_amdgcn_s_sleep(1);
    }
}

// per-pixel warp + bilinear + residual; TG fragment in registers (bfex form)
__device__ __forceinline__ void pixel_accum(
    const uint4* __restrict__ imgT,
    const uint4 t0, const uint4 g0, const uint4 g1,
    int b, int x, int y,
    float h00, float h01, float h02, float h10, float h11, float h12,
    float h20, float h21, float* aa) {
    const float X = (float)x - 127.5f, Y = (float)y - 127.5f;
    const float zw = h20 * X + h21 * Y + 1.f;
    const float Xw = (h00 * X + h01 * Y + h02) / zw + 127.5f;
    const float Yw = (h10 * X + h11 * Y + h12) / zw + 127.5f;
    const float NLO = -1.f + 2.f / 256.f, NHI = 1.f - 2.f / 256.f;
    const float xn = Xw / 127.5f - 1.f, yn = Yw / 127.5f - 1.f;
    const float m = (xn > NLO && xn < NHI && yn > NLO && yn < NHI) ? 1.f : 0.f;

    const float x0f = floorf(Xw), y0f = floorf(Yw);
    const float fx = Xw - x0f, fy = Yw - y0f;
    const float x1f = x0f + 1.f, y1f = y0f + 1.f;
    const bool vx0 = (x0f >= 0.f) && (x0f <= 255.f);
    const bool vx1 = (x1f >= 0.f) && (x1f <= 255.f);
    const bool vy0 = (y0f >= 0.f) && (y0f <= 255.f);
    const bool vy1 = (y1f >= 0.f) && (y1f <= 255.f);
    const int xi0 = (int)fminf(fmaxf(x0f, 0.f), 255.f);
    const int xi1 = (int)fminf(fmaxf(x1f, 0.f), 255.f);
    const int yi0 = (int)fminf(fmaxf(y0f, 0.f), 255.f);
    const int yi1 = (int)fminf(fmaxf(y1f, 0.f), 255.f);
    const int i00 = yi0 * W_ + xi0, i01 = yi0 * W_ + xi1;
    const int i10 = yi1 * W_ + xi0, i11 = yi1 * W_ + xi1;
    const float w00 = ((vx0 && vy0) ? 1.f : 0.f) * (1.f - fx) * (1.f - fy);
    const float w01 = ((vx1 && vy0) ? 1.f : 0.f) * fx * (1.f - fy);
    const float w10 = ((vx0 && vy1) ? 1.f : 0.f) * (1.f - fx) * fy;
    const float w11 = ((vx1 && vy1) ? 1.f : 0.f) * fx * fy;

    const int base = b * HW;
    const uint4 u00 = imgT[base + i00], u01 = imgT[base + i01];
    const uint4 u10 = imgT[base + i10], u11 = imgT[base + i11];

    float vx = 0.f, vy = 0.f;
    #pragma unroll
    for (int c = 0; c < 8; ++c) {
        const float Q = w00 * bfex(u00, c) + w01 * bfex(u01, c)
                      + w10 * bfex(u10, c) + w11 * bfex(u11, c);
        const float r = Q - bfex(t0, c) * m;
        vx += bfex(g0, c) * r;
        vy += bfex(g1, c) * r;
    }
    const float t0a = X * vx, t4a = Y * vy;
    const float cc = t0a + t4a;
    aa[0] += t0a;      aa[1] += Y * vx;  aa[2] += vx;
    aa[3] += X * vy;   aa[4] += t4a;     aa[5] += vy;
    aa[6] -= X * cc;   aa[7] -= Y * cc;
}

// ---------------------------------------------------------------------------
// prep: R10's proven 2048-block staged kernel (~15 µs, full BW), planar TG,
// plain cached stores (dispatch boundary = visibility). Blocks 0..7 also
// zero the fused kernel's flag region (641 words per batch, plain stores).
// ---------------------------------------------------------------------------
__global__ __launch_bounds__(256) void prep_kernel(
    const float* __restrict__ img, const float* __restrict__ temp,
    uint4* __restrict__ imgT, uint4* __restrict__ TGt,
    uint4* __restrict__ TGx, uint4* __restrict__ TGy,
    double* __restrict__ gramP,
    unsigned int* __restrict__ iterFlags, unsigned int* __restrict__ invHflag) {
    __shared__ float smem[8192];
    __shared__ float s15[15];
    const int b   = blockIdx.x & 7;
    const int y   = blockIdx.x >> 3;
    const int tid = threadIdx.x;

    if (blockIdx.x < 8) {   // y==0 blocks: zero flags for batch b
        for (int s = tid; s < 641; s += 256) {
            if (s < 640) iterFlags[((size_t)blockIdx.x * 640 + s) * 16] = 0u;
            else         invHflag[blockIdx.x * 16] = 0u;
        }
    }

    const int ym = (y > 0) ? y - 1 : 0;
    const int yp = (y < 255) ? y + 1 : 255;

    #pragma unroll
    for (int j = 0; j < 8; ++j) {
        const int slot = tid + 256 * j;
        const int rowid = slot >> 6, col4 = slot & 63;
        const int c = rowid >> 2, sel = rowid & 3;
        const int sy = (sel == 0) ? ym : ((sel == 2) ? yp : y);
        const float* src = ((sel == 3) ? img : temp)
                         + ((size_t)(b * K_ + c) * HW + sy * W_ + col4 * 4);
        const float4 v = *(const float4*)src;
        *(float4*)&smem[(c * 4 + sel) * 256 + col4 * 4] = v;
    }
    __syncthreads();

    const int x = tid;
    const int px = (y << 8) | x;
    const float X = (float)x - 127.5f, Y = (float)y - 127.5f;
    const int xm = (x > 0) ? x - 1 : 0;
    const int xp = (x < 255) ? x + 1 : 255;
    float Sxx = 0.f, Sxy = 0.f, Syy = 0.f;
    unsigned int imgp[4] = {0, 0, 0, 0};
    unsigned int tgp[12];
    #pragma unroll
    for (int i = 0; i < 12; ++i) tgp[i] = 0u;
    #pragma unroll
    for (int c = 0; c < 8; ++c) {
        const float* R = &smem[c * 1024];
        const float gx = 0.5f * (R[256 + xp] - R[256 + xm]);
        const float gy = 0.5f * (R[512 + x] - R[x]);
        const float tc = R[256 + x];
        const float iv = R[768 + x];
        Sxx += gx * gx; Sxy += gx * gy; Syy += gy * gy;
        const int sh = (c & 1) * 16;
        imgp[c >> 1]     |= ((unsigned int)f2bf(iv)) << sh;
        tgp[c >> 1]      |= ((unsigned int)f2bf(tc)) << sh;
        tgp[4 + (c >> 1)]|= ((unsigned int)f2bf(gx)) << sh;
        tgp[8 + (c >> 1)]|= ((unsigned int)f2bf(gy)) << sh;
    }
    const size_t gpx = (size_t)b * HW + px;
    imgT[gpx] = make_uint4(imgp[0], imgp[1], imgp[2], imgp[3]);
    TGt[gpx] = make_uint4(tgp[0], tgp[1], tgp[2],  tgp[3]);
    TGx[gpx] = make_uint4(tgp[4], tgp[5], tgp[6],  tgp[7]);
    TGy[gpx] = make_uint4(tgp[8], tgp[9], tgp[10], tgp[11]);
    __syncthreads();   // rows consumed; reuse smem for the moment reduce

    {
        const float X2 = X * X;
        const float Xp[5] = {1.f, X, X2, X2 * X, X2 * X2};
        #pragma unroll
        for (int n = 0; n < 5; ++n) {
            smem[n * 256 + tid]        = Sxx * Xp[n];
            smem[(5 + n) * 256 + tid]  = Sxy * Xp[n];
            smem[(10 + n) * 256 + tid] = Syy * Xp[n];
        }
    }
    __syncthreads();
    {
        const int e = tid >> 5, l = tid & 31;
        float v = 0.f;
        #pragma unroll
        for (int j = 0; j < 8; ++j) v += smem[e * 256 + l + 32 * j];
        v = half_reduce(v);
        if (l == 0) s15[e] = v;
    }
    if (tid < 224) {
        const int e = 8 + (tid >> 5), l = tid & 31;
        float v = 0.f;
        #pragma unroll
        for (int j = 0; j < 8; ++j) v += smem[e * 256 + l + 32 * j];
        v = half_reduce(v);
        if ((tid & 31) == 0) s15[e] = v;
    }
    __syncthreads();

    if (tid < 36) {
        const int aC[8]  = {1, 1, 1, 0, 0, 0, -1, -1};
        const int aNX[8] = {1, 0, 0, 0, 0, 0,  2,  1};
        const int aNY[8] = {0, 1, 0, 0, 0, 0,  0,  1};
        const int bC[8]  = {0, 0, 0, 1, 1, 1, -1, -1};
        const int bNX[8] = {0, 0, 0, 1, 0, 0,  1,  0};
        const int bNY[8] = {0, 0, 0, 0, 1, 0,  1,  2};
        const double Yd = (double)Y;
        const double Yp2 = Yd * Yd;
        const double Ypw[5] = {1.0, Yd, Yp2, Yp2 * Yd, Yp2 * Yp2};
        int p = 0, rem = tid;
        while (rem >= 8 - p) { rem -= 8 - p; ++p; }
        const int q = p + rem;
        double g = 0.0;
        const int ac = aC[p] * aC[q];
        if (ac) g += ac * Ypw[aNY[p] + aNY[q]] * (double)s15[aNX[p] + aNX[q]];
        const int ab1 = aC[p] * bC[q];
        if (ab1) g += ab1 * Ypw[aNY[p] + bNY[q]] * (double)s15[5 + aNX[p] + bNX[q]];
        const int ab2 = bC[p] * aC[q];
        if (ab2) g += ab2 * Ypw[bNY[p] + aNY[q]] * (double)s15[5 + bNX[p] + aNX[q]];
        const int bc = bC[p] * bC[q];
        if (bc) g += bc * Ypw[bNY[p] + bNY[q]] * (double)s15[10 + bNX[p] + bNX[q]];
        gramP[((size_t)b * 36 + tid) * 256 + y] = g;
    }
}

// ---------------------------------------------------------------------------
// fused iterations: R3's proven 512-block engine (4 px/thread, TG in regs,
// b=blockIdx&7 -> batch is XCD-local) with FLAG barriers replacing the
// serialized RMW counter: arrive = one coherent store to the block's OWN
// cacheline; wait = lanes 0..63 poll 64 flags in parallel (ballot).
// invH computed on (yb==0) during iter 0, published via single-writer flag.
// Output folded in. 512 blocks x 256 thr: residency guaranteed by capacity
// (proven R3/R5); all spins bounded -> worst case fast-fail, never a hang.
// ---------------------------------------------------------------------------
__global__ __launch_bounds__(256, 2) void fused_kernel(
    const uint4* __restrict__ imgT,
    const uint4* __restrict__ TGt, const uint4* __restrict__ TGx,
    const uint4* __restrict__ TGy,
    const double* __restrict__ gramP, double* __restrict__ invHg,
    const float* __restrict__ init_param,
    float* __restrict__ sP0, float* __restrict__ sP1,
    unsigned int* __restrict__ iterFlags, unsigned int* __restrict__ invHflag,
    const int* __restrict__ max_itr, float* __restrict__ out) {
    __shared__ float red[2048];
    __shared__ float s8[8];
    __shared__ double sh_invH[64];
    __shared__ double sh_pd[16];      // p (0..7), dp (8..15)
    __shared__ float sh_pf[8];
    __shared__ double gpart[144];
    __shared__ double shA[64], shB[64];

    const int tid = threadIdx.x;
    const int b   = blockIdx.x & 7;
    const int yb  = blockIdx.x >> 3;       // 0..63, rows 4*yb..4*yb+3
    const int mi_raw = *max_itr;
    const int mi = (mi_raw > 10) ? 10 : mi_raw;

    // ---- TG slice into registers (planar loads; each thread keeps 4 px) ----
    uint4 rT[4], rGX[4], rGY[4];
    {
        const size_t base = (size_t)b * HW + (size_t)yb * 1024 + tid;
        #pragma unroll
        for (int sub = 0; sub < 4; ++sub) {
            const size_t px = base + (size_t)(sub * 256);
            rT[sub] = TGt[px]; rGX[sub] = TGx[px]; rGY[sub] = TGy[px];
        }
    }

    for (int it = 0; it < mi; ++it) {
        if (it > 0) {
            // ---- wait: 64 parallel flag polls (wave 0), no RMW chain ----
            if (tid < 64) wait_flags64(&iterFlags[(size_t)(b * 640 + (it - 1) * 64) * 16], tid);
            if (it == 1 && tid == 0) wait_count(&invHflag[b * 16], 1u);
            __syncthreads();
            if (it == 1 && tid < 64) sh_invH[tid] = cloadd(&invHg[b * 64 + tid]);
            // ---- state reconstruction (coherent reads; identical FP/block) ----
            {
                const float* sR = ((it & 1) ? sP0 : sP1) + b * 512;
                const int e = tid >> 5, l = tid & 31;
                float v = cloadf(&sR[e * 64 + l]) + cloadf(&sR[e * 64 + 32 + l]);
                v = half_reduce(v);
                if (l == 0) s8[e] = v;
            }
            __syncthreads();
            if (tid < 8) {
                double nrm2 = 0.0;
                #pragma unroll
                for (int k2 = 0; k2 < 8; ++k2) {
                    const double d = sh_pd[8 + k2];
                    nrm2 += d * d;
                }
                double dpn = 0.0;
                if (tid < 6) {
                    #pragma unroll
                    for (int k2 = 0; k2 < 8; ++k2)
                        dpn += sh_invH[tid * 8 + k2] * (double)s8[k2];
                }
                const double dp2 = (sqrt(nrm2) > 1e-3) ? dpn : 0.0;
                const double pnew = sh_pd[tid] - dp2;
                sh_pd[tid]     = pnew;
                sh_pd[8 + tid] = dp2;
            }
            __syncthreads();
        } else {
            if (tid < 8) {
                sh_pd[tid]     = (double)init_param[b * 8 + tid];
                sh_pd[8 + tid] = 1.0;
            }
            __syncthreads();
        }

        const float h00 = 1.f + (float)sh_pd[0], h01 = (float)sh_pd[1], h02 = (float)sh_pd[2];
        const float h10 = (float)sh_pd[3], h11 = 1.f + (float)sh_pd[4], h12 = (float)sh_pd[5];
        const float h20 = (float)sh_pd[6], h21 = (float)sh_pd[7];

        // ---- pixel phase: 4 px/thread fully unrolled (16 gathers) ----
        float aa[8];
        #pragma unroll
        for (int e = 0; e < 8; ++e) aa[e] = 0.f;
        #pragma unroll
        for (int sub = 0; sub < 4; ++sub) {
            pixel_accum(imgT, rT[sub], rGX[sub], rGY[sub], b, tid, yb * 4 + sub,
                        h00, h01, h02, h10, h11, h12, h20, h21, aa);
        }

        // ---- block reduce -> 8 coherent partial stores per block ----
        #pragma unroll
        for (int e = 0; e < 8; ++e) red[e * 256 + tid] = aa[e];
        __syncthreads();
        {
            const int e = tid >> 5, l = tid & 31;
            float v = 0.f;
            #pragma unroll
            for (int j = 0; j < 8; ++j) v += red[e * 256 + l + 32 * j];
            v = half_reduce(v);
            if (l == 0) {
                float* sW = (it & 1) ? sP1 : sP0;
                cstoref(&sW[b * 512 + e * 64 + yb], v);
            }
        }

        // ---- arrive: drain partials, then one flag store (own line) ----
        asm volatile("s_waitcnt vmcnt(0)" ::: "memory");
        __syncthreads();
        if (tid == 0)
            cstoreu(&iterFlags[(size_t)(b * 640 + it * 64 + yb) * 16], 1u);

        // ---- iter 0, yb==0: Gram reduce + f64 Gauss-Jordan, publish invH ----
        if (it == 0 && yb == 0) {
            if (tid < 144) {
                const int e = tid >> 2, q = tid & 3;
                const double* gp = gramP + ((size_t)b * 36 + e) * 256 + q * 64;
                double acc = 0.0;
                #pragma unroll 8
                for (int i = 0; i < 64; ++i) acc += gp[i];
                gpart[tid] = acc;
            }
            __syncthreads();
            const int i = tid >> 3, j = tid & 7;
            if (tid < 64) {
                const int pp = min(i, j), qq = max(i, j);
                const int tri = 8 * pp - (pp * (pp - 1)) / 2 + (qq - pp);
                shA[tid] = gpart[tri * 4] + gpart[tri * 4 + 1]
                         + gpart[tri * 4 + 2] + gpart[tri * 4 + 3];
                shB[tid] = (i == j) ? 1.0 : 0.0;
            }
            __syncthreads();
            for (int k = 0; k < 8; ++k) {
                const double piv = shA[k * 8 + k];
                __syncthreads();
                if (tid < 64 && i == k) { shA[tid] /= piv; shB[tid] /= piv; }
                __syncthreads();
                double f = 0, ak = 0, bk = 0;
                if (tid < 64) { f = shA[i * 8 + k]; ak = shA[k * 8 + j]; bk = shB[k * 8 + j]; }
                __syncthreads();
                if (tid < 64 && i != k) { shA[tid] -= f * ak; shB[tid] -= f * bk; }
                __syncthreads();
            }
            if (tid < 64) { cstored(&invHg[b * 64 + tid], shB[tid]);
                            sh_invH[tid] = shB[tid]; }   // stash (mi==1 output)
            asm volatile("s_waitcnt vmcnt(0)" ::: "memory");
            __syncthreads();
            if (tid == 0) cstoreu(&invHflag[b * 16], 1u);
        }
    }

    // ========================= OUTPUT phase ================================
    if (yb != 0) return;                  // 8 blocks, one per batch
    if (mi <= 0) {
        if (tid < 8) out[b * 8 + tid] = init_param[b * 8 + tid];
        if (tid < 9) {
            float v = (tid < 8) ? init_param[b * 8 + tid] : 0.f;
            if (tid == 0 || tid == 4 || tid == 8) v += 1.f;
            out[64 + b * 9 + tid] = v;
        }
        return;
    }
    if (tid < 64) wait_flags64(&iterFlags[(size_t)(b * 640 + (mi - 1) * 64) * 16], tid);
    __syncthreads();
    // sh_invH present: stashed at it==0 (covers mi==1) or loaded at it==1.
    {
        const float* sb = (((mi - 1) & 1) ? sP1 : sP0) + b * 512;
        const int e = tid >> 5, l = tid & 31;
        float v = cloadf(&sb[e * 64 + l]) + cloadf(&sb[e * 64 + 32 + l]);
        v = half_reduce(v);
        if (l == 0) s8[e] = v;
    }
    __syncthreads();
    if (tid < 8) {
        double nrm2 = 0.0;
        #pragma unroll
        for (int k2 = 0; k2 < 8; ++k2) {
            const double d = sh_pd[8 + k2];     // dp of last iteration
            nrm2 += d * d;
        }
        double dpn = 0.0;
        if (tid < 6) {
            #pragma unroll
            for (int k2 = 0; k2 < 8; ++k2)
                dpn += sh_invH[tid * 8 + k2] * (double)s8[k2];
        }
        const double dp2 = (sqrt(nrm2) > 1e-3) ? dpn : 0.0;
        const float pf = (float)(sh_pd[tid] - dp2);
        sh_pf[tid] = pf;
        out[b * 8 + tid] = pf;
    }
    __syncthreads();
    if (tid < 9) {
        float v2 = (tid < 8) ? sh_pf[tid] : 0.f;
        if (tid == 0 || tid == 4 || tid == 8) v2 += 1.f;
        out[64 + b * 9 + tid] = v2;
    }
}

extern "C" void kernel_launch(void* const* d_in, const int* in_sizes, int n_in,
                              void* d_out, int out_size, void* d_ws, size_t ws_size,
                              hipStream_t stream) {
    const float* img        = (const float*)d_in[0];
    const float* temp       = (const float*)d_in[1];
    const float* init_param = (const float*)d_in[2];
    const int*   max_itr    = (const int*)d_in[3];
    float* out = (float*)d_out;

    char* w = (char*)d_ws;
    double* gramP = (double*)w;                        // 576 KB
    double* invHg = gramP + 73728;                     // 4 KB
    float*  sP0   = (float*)(invHg + 512);             // 16 KB
    float*  sP1   = sP0 + 4096;                        // 16 KB
    unsigned int* iterFlags = (unsigned int*)(sP1 + 4096);   // 8*640*64B = 320 KB
    unsigned int* invHflag  = iterFlags + 8 * 640 * 16;      // 8 * 64 B
    uint4* imgT   = (uint4*)(w + 1048576);             // 8.39 MB (bf16 x8 / px)
    uint4* TGt    = (uint4*)(w + 1048576 + 8388608);   // planar T / GX / GY
    uint4* TGx    = TGt + (size_t)B_ * HW;
    uint4* TGy    = TGx + (size_t)B_ * HW;

    prep_kernel<<<B_ * H_, 256, 0, stream>>>(img, temp, imgT, TGt, TGx, TGy,
                                             gramP, iterFlags, invHflag);
    // 512 blocks == 256 CU x 2: residency by capacity (LDS ~11 KB, VGPR free)
    fused_kernel<<<512, 256, 0, stream>>>(imgT, TGt, TGx, TGy, gramP, invHg,
                                          init_param, sP0, sP1,
                                          iterFlags, invHflag, max_itr, out);
}